// Round 8
// baseline (236.242 us; speedup 1.0000x reference)
//
#include <hip/hip_runtime.h>
#include <hip/hip_bf16.h>

#define BB 4
#define NN 32768
#define MM 8192
#define KK 16
#define DD 128
#define DOUT 128
#define TT 2048

typedef unsigned short ushortT;
typedef unsigned int uintT;
typedef __attribute__((ext_vector_type(8))) short short8;
typedef __attribute__((ext_vector_type(4))) float f32x4;
typedef __attribute__((ext_vector_type(2))) float f32x2;

__device__ __forceinline__ ushortT f2bf(float f) {
  union { float f; uintT u; } v; v.f = f;
  uintT u = v.u;
  return (ushortT)((u + 0x7FFFu + ((u >> 16) & 1u)) >> 16);
}

// stats layout (floats) in ws
#define ST_MAXD 0
#define ST_E1 16     // [b*32 + o] = sum, [b*32 + 16 + o] = sumsq
#define ST_A1 160
#define ST_B1 224
#define ST_E2 288
#define ST_A2 416
#define ST_B2 480

// ---------------- transpose x (B,D,N) f32 -> xTb (B,N,D) bf16 ----------------
__global__ __launch_bounds__(256) void kxT(const float* __restrict__ x, ushortT* __restrict__ xTb) {
  __shared__ float tile[32][33];
  const int b = blockIdx.z;
  const int n0 = blockIdx.x * 32, d0 = blockIdx.y * 32;
  const int tx = threadIdx.x, ty = threadIdx.y;
  const float* xp = x + (size_t)b * DD * NN;
  #pragma unroll
  for (int i = 0; i < 4; i++)
    tile[ty + i * 8][tx] = xp[(size_t)(d0 + ty + i * 8) * NN + n0 + tx];
  __syncthreads();
  ushortT* op = xTb + (size_t)b * NN * DD;
  #pragma unroll
  for (int i = 0; i < 4; i++)
    op[(size_t)(n0 + ty + i * 8) * DD + d0 + tx] = f2bf(tile[tx][ty + i * 8]);
}

// ---------------- cv_w f32 -> bf16 ----------------
__global__ __launch_bounds__(256) void kWb(const float* __restrict__ cw, ushortT* __restrict__ wb) {
  const int i = blockIdx.x * 256 + threadIdx.x;
  wb[i] = f2bf(cw[i]);
}

// ---------------- pass A: mean_radius + e1 stats + write pts4 ----------------
__global__ __launch_bounds__(256) void kpassA(const float* __restrict__ xyz,
    const float* __restrict__ xyzc, const int* __restrict__ idx,
    const float* __restrict__ w1, float* __restrict__ st, float4* __restrict__ pts4) {
  const int b = blockIdx.y;
  const int tid = threadIdx.x;
  const int mloc = tid >> 4, k = tid & 15;
  const int m = blockIdx.x * 16 + mloc;
  const int gi = (b * MM + m) * KK + k;
  const int n = idx[gi];
  const float cx = xyzc[(b * MM + m) * 3 + 0];
  const float cy = xyzc[(b * MM + m) * 3 + 1];
  const float cz = xyzc[(b * MM + m) * 3 + 2];
  const float* p = xyz + ((size_t)b * NN + n) * 3;
  const float px = p[0] - cx, py = p[1] - cy, pz = p[2] - cz;
  const float dist = sqrtf(px * px + py * py + pz * pz);
  pts4[gi] = (float4){px, py, pz, dist};
  float maxd = dist;
  maxd = fmaxf(maxd, __shfl_xor(maxd, 1));
  maxd = fmaxf(maxd, __shfl_xor(maxd, 2));
  maxd = fmaxf(maxd, __shfl_xor(maxd, 4));
  maxd = fmaxf(maxd, __shfl_xor(maxd, 8));
  __shared__ float red[16];
  __shared__ float wred[4][32];
  if (k == 0) red[mloc] = maxd;
  float vs[16], vq[16];
  #pragma unroll
  for (int o = 0; o < 16; o++) {
    float e = px * w1[3 * o] + py * w1[3 * o + 1] + pz * w1[3 * o + 2];
    vs[o] = e; vq[o] = e * e;
  }
  #pragma unroll
  for (int s = 1; s < 64; s <<= 1) {
    #pragma unroll
    for (int o = 0; o < 16; o++) {
      vs[o] += __shfl_xor(vs[o], s);
      vq[o] += __shfl_xor(vq[o], s);
    }
  }
  const int wv = tid >> 6, lane = tid & 63;
  if (lane == 0) {
    #pragma unroll
    for (int o = 0; o < 16; o++) { wred[wv][o] = vs[o]; wred[wv][16 + o] = vq[o]; }
  }
  __syncthreads();
  if (tid < 32) {
    float a = wred[0][tid] + wred[1][tid] + wred[2][tid] + wred[3][tid];
    atomicAdd(&st[ST_E1 + b * 32 + tid], a);
  }
  if (tid == 0) {
    float s = 0.f;
    #pragma unroll
    for (int i = 0; i < 16; i++) s += red[i];
    atomicAdd(&st[ST_MAXD], s);
  }
}

// ---------------- finalize 1: nr, A1/B1 ----------------
__global__ void kS1(const float* __restrict__ nrad, const float* __restrict__ g1,
                    const float* __restrict__ b1, float* __restrict__ st) {
  const int tid = threadIdx.x;
  if (tid >= 64) return;
  const float meanrad = st[ST_MAXD] / (float)(BB * MM);
  const float nr = nrad[0] * 0.9f + meanrad * 0.1f;
  const int b = tid >> 4, o = tid & 15;
  const float cnt = (float)(MM * KK);
  const float sum = st[ST_E1 + b * 32 + o];
  const float sq  = st[ST_E1 + b * 32 + 16 + o];
  const float mu = sum / cnt;
  float var = sq / cnt - mu * mu; var = fmaxf(var, 0.f);
  const float invs = rsqrtf(var + 1e-5f * nr * nr);
  const float a = invs * g1[o];
  st[ST_A1 + b * 16 + o] = a;
  st[ST_B1 + b * 16 + o] = b1[o] - mu * a;
}

// ---------------- pass B: e2 stats (pure stream from pts4) ----------------
__global__ __launch_bounds__(256) void kpassB(const float4* __restrict__ pts4,
    const float* __restrict__ alpha, const float* __restrict__ beta,
    const float* __restrict__ w1, const float* __restrict__ w2,
    float* __restrict__ st) {
  const int b = blockIdx.y;
  const int tid = threadIdx.x;
  __shared__ float wred[4][32];
  const int gi = b * MM * KK + blockIdx.x * 256 + tid;
  const float4 p4 = pts4[gi];
  const float px = p4.x, py = p4.y, pz = p4.z, dist = p4.w;
  float dwv = 1.f / (1.f + expf(alpha[0] * dist - beta[0]));
  float s = dwv;
  s += __shfl_xor(s, 1); s += __shfl_xor(s, 2); s += __shfl_xor(s, 4); s += __shfl_xor(s, 8);
  s = s + (s == 0.f ? 1.f : 0.f) + 1e-6f;
  dwv = dwv / s * 16.f;
  f32x2 v1[16];
  #pragma unroll
  for (int o = 0; o < 16; o++) {
    float e = px * w1[3 * o] + py * w1[3 * o + 1] + pz * w1[3 * o + 2];
    float v = e * st[ST_A1 + b * 16 + o] + st[ST_B1 + b * 16 + o];
    v = fmaxf(v, 0.f);
    float t = v * dwv;
    t = fmaxf(t, __shfl_xor(t, 1)); t = fmaxf(t, __shfl_xor(t, 2));
    t = fmaxf(t, __shfl_xor(t, 4)); t = fmaxf(t, __shfl_xor(t, 8));
    if (o & 1) { v1[o >> 1].y = v; v1[8 + (o >> 1)].y = t; }
    else       { v1[o >> 1].x = v; v1[8 + (o >> 1)].x = t; }
  }
  float vs[16], vq[16];
  #pragma unroll
  for (int o = 0; o < 16; o++) {
    f32x2 acc = {0.f, 0.f};
    #pragma unroll
    for (int cp = 0; cp < 16; cp++) {
      const f32x2 wv = *(const f32x2*)(w2 + o * 32 + 2 * cp);
      acc += v1[cp] * wv;
    }
    const float e = acc.x + acc.y;
    vs[o] = e; vq[o] = e * e;
  }
  #pragma unroll
  for (int s2 = 1; s2 < 64; s2 <<= 1) {
    #pragma unroll
    for (int o = 0; o < 16; o++) {
      vs[o] += __shfl_xor(vs[o], s2);
      vq[o] += __shfl_xor(vq[o], s2);
    }
  }
  const int wv = tid >> 6, lane = tid & 63;
  if (lane == 0) {
    #pragma unroll
    for (int o = 0; o < 16; o++) { wred[wv][o] = vs[o]; wred[wv][16 + o] = vq[o]; }
  }
  __syncthreads();
  if (tid < 32) {
    float a = wred[0][tid] + wred[1][tid] + wred[2][tid] + wred[3][tid];
    atomicAdd(&st[ST_E2 + b * 32 + tid], a);
  }
}

// ---------------- finalize 2: A2/B2 ----------------
__global__ void kS2(const float* __restrict__ g2, const float* __restrict__ b2,
                    float* __restrict__ st) {
  const int tid = threadIdx.x;
  if (tid >= 64) return;
  const int b = tid >> 4, o = tid & 15;
  const float cnt = (float)(MM * KK);
  const float sum = st[ST_E2 + b * 32 + o];
  const float sq  = st[ST_E2 + b * 32 + 16 + o];
  const float mu = sum / cnt;
  float var = sq / cnt - mu * mu; var = fmaxf(var, 0.f);
  const float invs = rsqrtf(var + 1e-5f);
  const float a = invs * g2[o];
  st[ST_A2 + b * 16 + o] = a;
  st[ST_B2 + b * 16 + o] = b2[o] - mu * a;
}

// ---------------- kMat3: phase-1 only (layers 1-3 -> mat3g, swizzled) --------
__global__ __launch_bounds__(256, 6) void kMat3(const float* __restrict__ xyz,
    const float* __restrict__ xyzc, const int* __restrict__ idx,
    const float* __restrict__ alpha, const float* __restrict__ beta,
    const float* __restrict__ w1, const float* __restrict__ w2,
    const float* __restrict__ w3, const float* __restrict__ st,
    float* __restrict__ mat3g) {
  const int b = blockIdx.y;
  const int tid = threadIdx.x;
  const int mloc = tid >> 4, k1 = tid & 15;
  const int m = blockIdx.x * 16 + mloc;
  const int gi = (b * MM + m) * KK + k1;
  const int n = idx[gi];
  const float cx = xyzc[(b * MM + m) * 3 + 0];
  const float cy = xyzc[(b * MM + m) * 3 + 1];
  const float cz = xyzc[(b * MM + m) * 3 + 2];
  const float* p = xyz + ((size_t)b * NN + n) * 3;
  const float px = p[0] - cx, py = p[1] - cy, pz = p[2] - cz;
  const float dist = sqrtf(px * px + py * py + pz * pz);
  float dwv = 1.f / (1.f + expf(alpha[0] * dist - beta[0]));
  {
    float s = dwv;
    s += __shfl_xor(s, 1); s += __shfl_xor(s, 2); s += __shfl_xor(s, 4); s += __shfl_xor(s, 8);
    s = s + (s == 0.f ? 1.f : 0.f) + 1e-6f;
    dwv = dwv / s * 16.f;
  }
  // layer 1 -> v1 pairs (R6 layout)
  f32x2 v1[16];
  #pragma unroll
  for (int o = 0; o < 16; o++) {
    float e = px * w1[3 * o] + py * w1[3 * o + 1] + pz * w1[3 * o + 2];
    float v = e * st[ST_A1 + b * 16 + o] + st[ST_B1 + b * 16 + o];
    v = fmaxf(v, 0.f);
    float t = v * dwv;
    t = fmaxf(t, __shfl_xor(t, 1)); t = fmaxf(t, __shfl_xor(t, 2));
    t = fmaxf(t, __shfl_xor(t, 4)); t = fmaxf(t, __shfl_xor(t, 8));
    if (o & 1) { v1[o >> 1].y = v; v1[8 + (o >> 1)].y = t; }
    else       { v1[o >> 1].x = v; v1[8 + (o >> 1)].x = t; }
  }
  // layer 2 (weights via s_load from global)
  float in2[16];
  #pragma unroll
  for (int o = 0; o < 16; o++) {
    f32x2 acc = {0.f, 0.f};
    #pragma unroll
    for (int cp = 0; cp < 16; cp++) {
      const f32x2 wv = *(const f32x2*)(w2 + o * 32 + 2 * cp);
      acc += v1[cp] * wv;
    }
    float v = (acc.x + acc.y) * st[ST_A2 + b * 16 + o] + st[ST_B2 + b * 16 + o];
    in2[o] = fmaxf(v, 0.f);
  }
  f32x2 v2[16];
  #pragma unroll
  for (int o = 0; o < 16; o++) {
    float t = in2[o] * dwv;
    t = fmaxf(t, __shfl_xor(t, 1)); t = fmaxf(t, __shfl_xor(t, 2));
    t = fmaxf(t, __shfl_xor(t, 4)); t = fmaxf(t, __shfl_xor(t, 8));
    if (o & 1) { v2[o >> 1].y = in2[o]; v2[8 + (o >> 1)].y = t; }
    else       { v2[o >> 1].x = in2[o]; v2[8 + (o >> 1)].x = t; }
  }
  // layer 3
  float m3v[16];
  #pragma unroll
  for (int j = 0; j < 16; j++) {
    f32x2 acc = {0.f, 0.f};
    #pragma unroll
    for (int cp = 0; cp < 16; cp++) {
      const f32x2 wv = *(const f32x2*)(w3 + j * 32 + 2 * cp);
      acc += v2[cp] * wv;
    }
    m3v[j] = fmaxf(acc.x + acc.y, 0.f) * dwv;
  }
  // coalesced swizzled store: per m, [k][16] with quad-XOR; tid covers 64B
  const int swz1 = (k1 ^ (k1 >> 2)) & 3;
  float* m3w = mat3g + (((size_t)b * MM + blockIdx.x * 16) << 8) + tid * 16;
  #pragma unroll
  for (int q = 0; q < 4; q++)
    *(f32x4*)(m3w + ((q ^ swz1) << 2)) =
        (f32x4){m3v[4 * q], m3v[4 * q + 1], m3v[4 * q + 2], m3v[4 * q + 3]};
}

// ---------------- kF2: gather contraction, m-pair dedup gathers --------------
// R8: R7 showed kF2 ~108us with every pipe <=56%/20% -- the constant across
// R1-R7 was the VMEM gather stream: 64 instrs/wave, 8B/lane, and lanes 0-31 /
// 32-63 read the SAME 256B row (jh duplication). VMEM front-end serializes
// per-instruction address processing -> that stream is the wall. Fix: wave
// covers an m-PAIR: lane = (mh = lane>>5, dq = lane&31); one gather reads two
// DIFFERENT rows (512B unique). Gathers/wave 64 -> 32; duplicate L2 traffic
// halved; no cross-lane combine needed (m's independent). acc = 4d x 16j =
// 64 f32 + 2x 16-load buffers -> (512,3) (170-reg budget). idx reads stay
// uniform s_load (mh-select via cndmask on literal-indexed scalars). Staging
// rewritten conflict-free (consecutive tid -> consecutive 16B).
__global__ __launch_bounds__(512, 3) void kF2(const int* __restrict__ idx,
    const float* __restrict__ mat3g, const ushortT* __restrict__ xTb,
    ushortT* __restrict__ Aout) {
  __shared__ float mat3s[32 * 256];
  const int b = blockIdx.y;
  const int tid = threadIdx.x;
  const int m0 = blockIdx.x * 32;

  const int wid = __builtin_amdgcn_readfirstlane(tid >> 6);
  const int lane = tid & 63;
  const int mh = lane >> 5;       // m-pair half
  const int dq = lane & 31;
  const int d0 = dq * 4;          // 4 d's per lane (uint2 = 4 bf16)
  const ushortT* xb = xTb + (size_t)b * NN * DD + d0;

  uint2 xA[16], xB[16];

#define PREF(dst, gg) do {                                                 \
    const int* ib0 = idx + ((b * MM + m0 + (gg) * 16 + wid * 2) << 4);     \
    const int* ib1 = ib0 + 16;                                             \
    _Pragma("unroll")                                                      \
    for (int t = 0; t < 16; t++) {                                         \
      const int ke = ib0[t], ko = ib1[t];                                  \
      const uintT nn = (uintT)(mh ? ko : ke);                              \
      (dst)[t] = *(const uint2*)(xb + ((size_t)nn << 7));                  \
    }                                                                      \
  } while (0)

  PREF(xA, 0);  // in flight under staging; drained by the barrier

  // stage mat3 tile, conflict-free: thread t copies 4x16B at t*16B + i*8KB
  {
    const f32x4* src = (const f32x4*)(mat3g + (((size_t)b * MM + m0) << 8));
    f32x4* dst = (f32x4*)mat3s;
    #pragma unroll
    for (int i = 0; i < 4; i++)
      dst[tid + i * 512] = src[tid + i * 512];
  }
  __syncthreads();

#define COMP(src, gg) do {                                                 \
    const float* m3base = &mat3s[((gg) * 16 + wid * 2 + mh) * 256];        \
    f32x2 a2[4][8];                                                        \
    _Pragma("unroll")                                                      \
    for (int d = 0; d < 4; d++)                                            \
      _Pragma("unroll")                                                    \
      for (int c = 0; c < 8; c++) a2[d][c] = (f32x2){0.f, 0.f};            \
    _Pragma("unroll")                                                      \
    for (int t = 0; t < 16; t++) {                                         \
      const int sw = (t ^ (t >> 2)) & 3;                                   \
      const uint2 xv = (src)[t];                                           \
      const f32x4 mq0 = *(const f32x4*)(m3base + t * 16 + ((0 ^ sw) << 2));\
      const f32x4 mq1 = *(const f32x4*)(m3base + t * 16 + ((1 ^ sw) << 2));\
      const f32x4 mq2 = *(const f32x4*)(m3base + t * 16 + ((2 ^ sw) << 2));\
      const f32x4 mq3 = *(const f32x4*)(m3base + t * 16 + ((3 ^ sw) << 2));\
      float xs[4];                                                         \
      xs[0] = __uint_as_float(xv.x << 16);                                 \
      xs[1] = __uint_as_float(xv.x & 0xFFFF0000u);                         \
      xs[2] = __uint_as_float(xv.y << 16);                                 \
      xs[3] = __uint_as_float(xv.y & 0xFFFF0000u);                         \
      f32x2 mp[8];                                                         \
      mp[0] = mq0.lo; mp[1] = mq0.hi;                                      \
      mp[2] = mq1.lo; mp[3] = mq1.hi;                                      \
      mp[4] = mq2.lo; mp[5] = mq2.hi;                                      \
      mp[6] = mq3.lo; mp[7] = mq3.hi;                                      \
      _Pragma("unroll")                                                    \
      for (int d = 0; d < 4; d++) {                                        \
        const float xd = xs[d];                                            \
        _Pragma("unroll")                                                  \
        for (int c = 0; c < 8; c++)                                        \
          a2[d][c] += mp[c] * xd;                                          \
      }                                                                    \
    }                                                                      \
    ushortT* aop = Aout + ((size_t)b * MM + m0 + (gg) * 16 + wid * 2 + mh) * TT + d0 * 16; \
    _Pragma("unroll")                                                      \
    for (int d = 0; d < 4; d++) {                                          \
      uintT u[8];                                                          \
      _Pragma("unroll")                                                    \
      for (int c = 0; c < 8; c++)                                          \
        u[c] = (uintT)f2bf(a2[d][c].x) | ((uintT)f2bf(a2[d][c].y) << 16);  \
      *(uint4*)(aop + d * 16)     = (uint4){u[0], u[1], u[2], u[3]};       \
      *(uint4*)(aop + d * 16 + 8) = (uint4){u[4], u[5], u[6], u[7]};       \
    }                                                                      \
  } while (0)

  PREF(xB, 1);
  COMP(xA, 0);
  COMP(xB, 1);

#undef PREF
#undef COMP
}

// ---------------- GEMM: out[b,o,m] = sum_t Wb[o,t] * Aout[b,m,t] ----------------
__global__ __launch_bounds__(512) void kgemm(const ushortT* __restrict__ Wb,
                                             const ushortT* __restrict__ Aout,
                                             float* __restrict__ out) {
  __shared__ ushortT At[128 * 40];
  __shared__ ushortT Bt[128 * 40];
  const int b = blockIdx.y;
  const int m0 = blockIdx.x * 128;
  const int tid = threadIdx.x;
  const int w = tid >> 6, l = tid & 63;
  const int ow = (w >> 2) * 64, mw = (w & 3) * 32;
  const int fr = l & 15, fg = l >> 4;
  f32x4 acc[4][2];
  #pragma unroll
  for (int i = 0; i < 4; i++)
    #pragma unroll
    for (int j = 0; j < 2; j++)
      acc[i][j] = (f32x4){0.f, 0.f, 0.f, 0.f};
  const int srow = tid >> 2, sk = (tid & 3) * 8;
  const ushortT* wp = Wb + srow * TT + sk;
  const ushortT* ap = Aout + ((size_t)b * MM + m0 + srow) * TT + sk;
  for (int k0 = 0; k0 < TT; k0 += 32) {
    uint4 wv = *(const uint4*)(wp + k0);
    uint4 av = *(const uint4*)(ap + k0);
    *(uint4*)&At[srow * 40 + sk] = wv;
    *(uint4*)&Bt[srow * 40 + sk] = av;
    __syncthreads();
    short8 a[4], bfrag[2];
    #pragma unroll
    for (int i = 0; i < 4; i++) a[i] = *(short8*)&At[(ow + i * 16 + fr) * 40 + fg * 8];
    #pragma unroll
    for (int j = 0; j < 2; j++) bfrag[j] = *(short8*)&Bt[(mw + j * 16 + fr) * 40 + fg * 8];
    #pragma unroll
    for (int i = 0; i < 4; i++)
      #pragma unroll
      for (int j = 0; j < 2; j++)
        acc[i][j] = __builtin_amdgcn_mfma_f32_16x16x32_bf16(a[i], bfrag[j], acc[i][j], 0, 0, 0);
    __syncthreads();
  }
  #pragma unroll
  for (int i = 0; i < 4; i++)
    #pragma unroll
    for (int j = 0; j < 2; j++)
      #pragma unroll
      for (int r = 0; r < 4; r++) {
        const int o = ow + i * 16 + fg * 4 + r;
        const int m = m0 + mw + j * 16 + fr;
        out[((size_t)b * DOUT + o) * MM + m] = acc[i][j][r];
      }
}

// ---------------- launch ----------------
#define XTB_OFF 0
#define PTS_OFF 33554432
#define MAT3_OFF 33554432   // aliases pts4: pts4 dead after kpassB; kMat3 recomputes pts
#define AOUT_OFF 67108864
#define WB_OFF 201326592
#define ST_OFF 201850880

extern "C" void kernel_launch(void* const* d_in, const int* in_sizes, int n_in,
                              void* d_out, int out_size, void* d_ws, size_t ws_size,
                              hipStream_t stream) {
  const float* xyz  = (const float*)d_in[0];
  const float* x    = (const float*)d_in[1];
  const float* xyzc = (const float*)d_in[2];
  const int*   idx  = (const int*)d_in[3];
  const float* alpha = (const float*)d_in[4];
  const float* beta  = (const float*)d_in[5];
  const float* nrad  = (const float*)d_in[6];
  const float* w1 = (const float*)d_in[7];
  const float* g1 = (const float*)d_in[8];
  const float* b1 = (const float*)d_in[9];
  const float* w2 = (const float*)d_in[10];
  const float* g2 = (const float*)d_in[11];
  const float* b2 = (const float*)d_in[12];
  const float* w3 = (const float*)d_in[13];
  const float* cvw = (const float*)d_in[14];
  char* ws = (char*)d_ws;
  ushortT* xTb  = (ushortT*)(ws + XTB_OFF);
  float4*  pts4 = (float4*)(ws + PTS_OFF);
  float*   mat3g = (float*)(ws + MAT3_OFF);
  ushortT* Aout = (ushortT*)(ws + AOUT_OFF);
  ushortT* Wb   = (ushortT*)(ws + WB_OFF);
  float*   st   = (float*)(ws + ST_OFF);
  float* out = (float*)d_out;

  hipMemsetAsync(st, 0, 4096, stream);
  kxT<<<dim3(NN / 32, DD / 32, BB), dim3(32, 8), 0, stream>>>(x, xTb);
  kWb<<<dim3(DOUT * TT / 256), 256, 0, stream>>>(cvw, Wb);
  kpassA<<<dim3(MM / 16, BB), 256, 0, stream>>>(xyz, xyzc, idx, w1, st, pts4);
  kS1<<<1, 64, 0, stream>>>(nrad, g1, b1, st);
  kpassB<<<dim3(MM / 16, BB), 256, 0, stream>>>(pts4, alpha, beta, w1, w2, st);
  kS2<<<1, 64, 0, stream>>>(g2, b2, st);
  kMat3<<<dim3(MM / 16, BB), 256, 0, stream>>>(xyz, xyzc, idx, alpha, beta, w1, w2, w3, st, mat3g);
  kF2<<<dim3(MM / 32, BB), 512, 0, stream>>>(idx, mat3g, xTb, Aout);
  kgemm<<<dim3(MM / 128, BB), 512, 0, stream>>>(Wb, Aout, out);
}

// Round 9
// 215.865 us; speedup vs baseline: 1.0944x; 1.0944x over previous
//
#include <hip/hip_runtime.h>
#include <hip/hip_bf16.h>

#define BB 4
#define NN 32768
#define MM 8192
#define KK 16
#define DD 128
#define DOUT 128
#define TT 2048

typedef unsigned short ushortT;
typedef unsigned int uintT;
typedef __attribute__((ext_vector_type(8))) short short8;
typedef __attribute__((ext_vector_type(4))) float f32x4;
typedef __attribute__((ext_vector_type(2))) float f32x2;

__device__ __forceinline__ ushortT f2bf(float f) {
  union { float f; uintT u; } v; v.f = f;
  uintT u = v.u;
  return (ushortT)((u + 0x7FFFu + ((u >> 16) & 1u)) >> 16);
}

// stats layout (floats) in ws
#define ST_MAXD 0
#define ST_E1 16     // [b*32 + o] = sum, [b*32 + 16 + o] = sumsq
#define ST_A1 160
#define ST_B1 224
#define ST_E2 288
#define ST_A2 416
#define ST_B2 480

// ---------------- transpose x (B,D,N) f32 -> xTb (B,N,D) bf16 ----------------
__global__ __launch_bounds__(256) void kxT(const float* __restrict__ x, ushortT* __restrict__ xTb) {
  __shared__ float tile[32][33];
  const int b = blockIdx.z;
  const int n0 = blockIdx.x * 32, d0 = blockIdx.y * 32;
  const int tx = threadIdx.x, ty = threadIdx.y;
  const float* xp = x + (size_t)b * DD * NN;
  #pragma unroll
  for (int i = 0; i < 4; i++)
    tile[ty + i * 8][tx] = xp[(size_t)(d0 + ty + i * 8) * NN + n0 + tx];
  __syncthreads();
  ushortT* op = xTb + (size_t)b * NN * DD;
  #pragma unroll
  for (int i = 0; i < 4; i++)
    op[(size_t)(n0 + ty + i * 8) * DD + d0 + tx] = f2bf(tile[tx][ty + i * 8]);
}

// ---------------- cv_w f32 -> bf16 ----------------
__global__ __launch_bounds__(256) void kWb(const float* __restrict__ cw, ushortT* __restrict__ wb) {
  const int i = blockIdx.x * 256 + threadIdx.x;
  wb[i] = f2bf(cw[i]);
}

// ---------------- pass A: mean_radius + e1 stats + write pts4 ----------------
__global__ __launch_bounds__(256) void kpassA(const float* __restrict__ xyz,
    const float* __restrict__ xyzc, const int* __restrict__ idx,
    const float* __restrict__ w1, float* __restrict__ st, float4* __restrict__ pts4) {
  const int b = blockIdx.y;
  const int tid = threadIdx.x;
  const int mloc = tid >> 4, k = tid & 15;
  const int m = blockIdx.x * 16 + mloc;
  const int gi = (b * MM + m) * KK + k;
  const int n = idx[gi];
  const float cx = xyzc[(b * MM + m) * 3 + 0];
  const float cy = xyzc[(b * MM + m) * 3 + 1];
  const float cz = xyzc[(b * MM + m) * 3 + 2];
  const float* p = xyz + ((size_t)b * NN + n) * 3;
  const float px = p[0] - cx, py = p[1] - cy, pz = p[2] - cz;
  const float dist = sqrtf(px * px + py * py + pz * pz);
  pts4[gi] = (float4){px, py, pz, dist};
  float maxd = dist;
  maxd = fmaxf(maxd, __shfl_xor(maxd, 1));
  maxd = fmaxf(maxd, __shfl_xor(maxd, 2));
  maxd = fmaxf(maxd, __shfl_xor(maxd, 4));
  maxd = fmaxf(maxd, __shfl_xor(maxd, 8));
  __shared__ float red[16];
  __shared__ float wred[4][32];
  if (k == 0) red[mloc] = maxd;
  float vs[16], vq[16];
  #pragma unroll
  for (int o = 0; o < 16; o++) {
    float e = px * w1[3 * o] + py * w1[3 * o + 1] + pz * w1[3 * o + 2];
    vs[o] = e; vq[o] = e * e;
  }
  #pragma unroll
  for (int s = 1; s < 64; s <<= 1) {
    #pragma unroll
    for (int o = 0; o < 16; o++) {
      vs[o] += __shfl_xor(vs[o], s);
      vq[o] += __shfl_xor(vq[o], s);
    }
  }
  const int wv = tid >> 6, lane = tid & 63;
  if (lane == 0) {
    #pragma unroll
    for (int o = 0; o < 16; o++) { wred[wv][o] = vs[o]; wred[wv][16 + o] = vq[o]; }
  }
  __syncthreads();
  if (tid < 32) {
    float a = wred[0][tid] + wred[1][tid] + wred[2][tid] + wred[3][tid];
    atomicAdd(&st[ST_E1 + b * 32 + tid], a);
  }
  if (tid == 0) {
    float s = 0.f;
    #pragma unroll
    for (int i = 0; i < 16; i++) s += red[i];
    atomicAdd(&st[ST_MAXD], s);
  }
}

// ---------------- finalize 1: nr, A1/B1 ----------------
__global__ void kS1(const float* __restrict__ nrad, const float* __restrict__ g1,
                    const float* __restrict__ b1, float* __restrict__ st) {
  const int tid = threadIdx.x;
  if (tid >= 64) return;
  const float meanrad = st[ST_MAXD] / (float)(BB * MM);
  const float nr = nrad[0] * 0.9f + meanrad * 0.1f;
  const int b = tid >> 4, o = tid & 15;
  const float cnt = (float)(MM * KK);
  const float sum = st[ST_E1 + b * 32 + o];
  const float sq  = st[ST_E1 + b * 32 + 16 + o];
  const float mu = sum / cnt;
  float var = sq / cnt - mu * mu; var = fmaxf(var, 0.f);
  const float invs = rsqrtf(var + 1e-5f * nr * nr);
  const float a = invs * g1[o];
  st[ST_A1 + b * 16 + o] = a;
  st[ST_B1 + b * 16 + o] = b1[o] - mu * a;
}

// ---------------- pass B: e2 stats (pure stream from pts4) ----------------
__global__ __launch_bounds__(256) void kpassB(const float4* __restrict__ pts4,
    const float* __restrict__ alpha, const float* __restrict__ beta,
    const float* __restrict__ w1, const float* __restrict__ w2,
    float* __restrict__ st) {
  const int b = blockIdx.y;
  const int tid = threadIdx.x;
  __shared__ float wred[4][32];
  const int gi = b * MM * KK + blockIdx.x * 256 + tid;
  const float4 p4 = pts4[gi];
  const float px = p4.x, py = p4.y, pz = p4.z, dist = p4.w;
  float dwv = 1.f / (1.f + expf(alpha[0] * dist - beta[0]));
  float s = dwv;
  s += __shfl_xor(s, 1); s += __shfl_xor(s, 2); s += __shfl_xor(s, 4); s += __shfl_xor(s, 8);
  s = s + (s == 0.f ? 1.f : 0.f) + 1e-6f;
  dwv = dwv / s * 16.f;
  f32x2 v1[16];
  #pragma unroll
  for (int o = 0; o < 16; o++) {
    float e = px * w1[3 * o] + py * w1[3 * o + 1] + pz * w1[3 * o + 2];
    float v = e * st[ST_A1 + b * 16 + o] + st[ST_B1 + b * 16 + o];
    v = fmaxf(v, 0.f);
    float t = v * dwv;
    t = fmaxf(t, __shfl_xor(t, 1)); t = fmaxf(t, __shfl_xor(t, 2));
    t = fmaxf(t, __shfl_xor(t, 4)); t = fmaxf(t, __shfl_xor(t, 8));
    if (o & 1) { v1[o >> 1].y = v; v1[8 + (o >> 1)].y = t; }
    else       { v1[o >> 1].x = v; v1[8 + (o >> 1)].x = t; }
  }
  float vs[16], vq[16];
  #pragma unroll
  for (int o = 0; o < 16; o++) {
    f32x2 acc = {0.f, 0.f};
    #pragma unroll
    for (int cp = 0; cp < 16; cp++) {
      const f32x2 wv = *(const f32x2*)(w2 + o * 32 + 2 * cp);
      acc += v1[cp] * wv;
    }
    const float e = acc.x + acc.y;
    vs[o] = e; vq[o] = e * e;
  }
  #pragma unroll
  for (int s2 = 1; s2 < 64; s2 <<= 1) {
    #pragma unroll
    for (int o = 0; o < 16; o++) {
      vs[o] += __shfl_xor(vs[o], s2);
      vq[o] += __shfl_xor(vq[o], s2);
    }
  }
  const int wv = tid >> 6, lane = tid & 63;
  if (lane == 0) {
    #pragma unroll
    for (int o = 0; o < 16; o++) { wred[wv][o] = vs[o]; wred[wv][16 + o] = vq[o]; }
  }
  __syncthreads();
  if (tid < 32) {
    float a = wred[0][tid] + wred[1][tid] + wred[2][tid] + wred[3][tid];
    atomicAdd(&st[ST_E2 + b * 32 + tid], a);
  }
}

// ---------------- finalize 2: A2/B2 ----------------
__global__ void kS2(const float* __restrict__ g2, const float* __restrict__ b2,
                    float* __restrict__ st) {
  const int tid = threadIdx.x;
  if (tid >= 64) return;
  const int b = tid >> 4, o = tid & 15;
  const float cnt = (float)(MM * KK);
  const float sum = st[ST_E2 + b * 32 + o];
  const float sq  = st[ST_E2 + b * 32 + 16 + o];
  const float mu = sum / cnt;
  float var = sq / cnt - mu * mu; var = fmaxf(var, 0.f);
  const float invs = rsqrtf(var + 1e-5f);
  const float a = invs * g2[o];
  st[ST_A2 + b * 16 + o] = a;
  st[ST_B2 + b * 16 + o] = b2[o] - mu * a;
}

// ---------------- kF1m: fused phase1 + m-pair gather contraction, 256 thr ----
// R9: R8 taught two things. (1) the m-pair dedup is real but its ~160-reg
// footprint at 512-thread blocks quantizes occupancy to 1 block/CU (8 waves,
// 21.8% measured) -- 256-thread blocks make the same footprint fit 3 blocks/CU
// (12 waves) at the same (.,3)=170-reg budget. (2) the R7 split was neutral on
// content (kMat3+kF2 ~= fused kF1) but pays kMat3 launch + 67MB mat3g round
// trip. So: re-fuse at 256 threads = 16 m/block (phase 1 maps exactly:
// 16m x 16k), keep R8's m-pair COMP. Pairs p = wid (xA) and wid+4 (xB).
// Spill tell: WRITE >> 140MB.
__global__ __launch_bounds__(256, 3) void kF1m(const float4* __restrict__ pts4,
    const int* __restrict__ idx,
    const float* __restrict__ alpha, const float* __restrict__ beta,
    const float* __restrict__ w1, const float* __restrict__ w2, const float* __restrict__ w3,
    const float* __restrict__ st, const ushortT* __restrict__ xTb, ushortT* __restrict__ Aout) {
  __shared__ float mat3s[16 * 256];   // 16KB
  const int b = blockIdx.y;
  const int tid = threadIdx.x;
  const int m0 = blockIdx.x * 16;

  // ---- phase 1: thread = (mloc = tid>>4, k1 = tid&15) ----
  const int mloc = tid >> 4, k1 = tid & 15;
  const int gi = (b * MM + m0) * KK + tid;
  const float4 p4 = pts4[gi];
  const float px = p4.x, py = p4.y, pz = p4.z, dist = p4.w;
  float dwv = 1.f / (1.f + expf(alpha[0] * dist - beta[0]));
  {
    float s = dwv;
    s += __shfl_xor(s, 1); s += __shfl_xor(s, 2); s += __shfl_xor(s, 4); s += __shfl_xor(s, 8);
    s = s + (s == 0.f ? 1.f : 0.f) + 1e-6f;
    dwv = dwv / s * 16.f;
  }
  // layer 1 -> v1 pairs
  f32x2 v1[16];
  #pragma unroll
  for (int o = 0; o < 16; o++) {
    float e = px * w1[3 * o] + py * w1[3 * o + 1] + pz * w1[3 * o + 2];
    float v = e * st[ST_A1 + b * 16 + o] + st[ST_B1 + b * 16 + o];
    v = fmaxf(v, 0.f);
    float t = v * dwv;
    t = fmaxf(t, __shfl_xor(t, 1)); t = fmaxf(t, __shfl_xor(t, 2));
    t = fmaxf(t, __shfl_xor(t, 4)); t = fmaxf(t, __shfl_xor(t, 8));
    if (o & 1) { v1[o >> 1].y = v; v1[8 + (o >> 1)].y = t; }
    else       { v1[o >> 1].x = v; v1[8 + (o >> 1)].x = t; }
  }

  // ---- phase-2 geometry + early prefetch (group A = pair wid) ----
  const int wid = __builtin_amdgcn_readfirstlane(tid >> 6);
  const int lane = tid & 63;
  const int mh = lane >> 5;
  const int dq = lane & 31;
  const int d0 = dq * 4;
  const ushortT* xb = xTb + (size_t)b * NN * DD + d0;

  uint2 xA[16], xB[16];

#define PREF(dst, p) do {                                                  \
    const int* ib0 = idx + ((b * MM + m0 + (p) * 2) << 4);                 \
    const int* ib1 = ib0 + 16;                                             \
    _Pragma("unroll")                                                      \
    for (int t = 0; t < 16; t++) {                                         \
      const int ke = ib0[t], ko = ib1[t];                                  \
      const uintT nn = (uintT)(mh ? ko : ke);                              \
      (dst)[t] = *(const uint2*)(xb + ((size_t)nn << 7));                  \
    }                                                                      \
  } while (0)

  PREF(xA, wid);  // in flight under layers 2/3

  // layers 2+3 (weights via s_load from global)
  {
    float in2[16];
    #pragma unroll
    for (int o = 0; o < 16; o++) {
      f32x2 acc = {0.f, 0.f};
      #pragma unroll
      for (int cp = 0; cp < 16; cp++) {
        const f32x2 wv = *(const f32x2*)(w2 + o * 32 + 2 * cp);
        acc += v1[cp] * wv;
      }
      float v = (acc.x + acc.y) * st[ST_A2 + b * 16 + o] + st[ST_B2 + b * 16 + o];
      in2[o] = fmaxf(v, 0.f);
    }
    f32x2 v2[16];
    #pragma unroll
    for (int o = 0; o < 16; o++) {
      float t = in2[o] * dwv;
      t = fmaxf(t, __shfl_xor(t, 1)); t = fmaxf(t, __shfl_xor(t, 2));
      t = fmaxf(t, __shfl_xor(t, 4)); t = fmaxf(t, __shfl_xor(t, 8));
      if (o & 1) { v2[o >> 1].y = in2[o]; v2[8 + (o >> 1)].y = t; }
      else       { v2[o >> 1].x = in2[o]; v2[8 + (o >> 1)].x = t; }
    }
    float m3v[16];
    #pragma unroll
    for (int j = 0; j < 16; j++) {
      f32x2 acc = {0.f, 0.f};
      #pragma unroll
      for (int cp = 0; cp < 16; cp++) {
        const f32x2 wv = *(const f32x2*)(w3 + j * 32 + 2 * cp);
        acc += v2[cp] * wv;
      }
      m3v[j] = fmaxf(acc.x + acc.y, 0.f) * dwv;
    }
    const int swz1 = (k1 ^ (k1 >> 2)) & 3;
    float* m3w = &mat3s[mloc * 256 + k1 * 16];
    #pragma unroll
    for (int q = 0; q < 4; q++)
      *(f32x4*)(m3w + ((q ^ swz1) << 2)) =
          (f32x4){m3v[4 * q], m3v[4 * q + 1], m3v[4 * q + 2], m3v[4 * q + 3]};
  }
  __syncthreads();  // mat3s ready (xA loads drained too)

#define COMP(src, p) do {                                                  \
    const float* m3base = &mat3s[((p) * 2 + mh) * 256];                    \
    f32x2 a2[4][8];                                                        \
    _Pragma("unroll")                                                      \
    for (int d = 0; d < 4; d++)                                            \
      _Pragma("unroll")                                                    \
      for (int c = 0; c < 8; c++) a2[d][c] = (f32x2){0.f, 0.f};            \
    _Pragma("unroll")                                                      \
    for (int t = 0; t < 16; t++) {                                         \
      const int sw = (t ^ (t >> 2)) & 3;                                   \
      const uint2 xv = (src)[t];                                           \
      const f32x4 mq0 = *(const f32x4*)(m3base + t * 16 + ((0 ^ sw) << 2));\
      const f32x4 mq1 = *(const f32x4*)(m3base + t * 16 + ((1 ^ sw) << 2));\
      const f32x4 mq2 = *(const f32x4*)(m3base + t * 16 + ((2 ^ sw) << 2));\
      const f32x4 mq3 = *(const f32x4*)(m3base + t * 16 + ((3 ^ sw) << 2));\
      float xs[4];                                                         \
      xs[0] = __uint_as_float(xv.x << 16);                                 \
      xs[1] = __uint_as_float(xv.x & 0xFFFF0000u);                         \
      xs[2] = __uint_as_float(xv.y << 16);                                 \
      xs[3] = __uint_as_float(xv.y & 0xFFFF0000u);                         \
      f32x2 mp[8];                                                         \
      mp[0] = mq0.lo; mp[1] = mq0.hi;                                      \
      mp[2] = mq1.lo; mp[3] = mq1.hi;                                      \
      mp[4] = mq2.lo; mp[5] = mq2.hi;                                      \
      mp[6] = mq3.lo; mp[7] = mq3.hi;                                      \
      _Pragma("unroll")                                                    \
      for (int d = 0; d < 4; d++) {                                        \
        const float xd = xs[d];                                            \
        _Pragma("unroll")                                                  \
        for (int c = 0; c < 8; c++)                                        \
          a2[d][c] += mp[c] * xd;                                          \
      }                                                                    \
    }                                                                      \
    ushortT* aop = Aout + ((size_t)b * MM + m0 + (p) * 2 + mh) * TT + d0 * 16; \
    _Pragma("unroll")                                                      \
    for (int d = 0; d < 4; d++) {                                          \
      uintT u[8];                                                          \
      _Pragma("unroll")                                                    \
      for (int c = 0; c < 8; c++)                                          \
        u[c] = (uintT)f2bf(a2[d][c].x) | ((uintT)f2bf(a2[d][c].y) << 16);  \
      *(uint4*)(aop + d * 16)     = (uint4){u[0], u[1], u[2], u[3]};       \
      *(uint4*)(aop + d * 16 + 8) = (uint4){u[4], u[5], u[6], u[7]};       \
    }                                                                      \
  } while (0)

  PREF(xB, wid + 4);
  COMP(xA, wid);
  COMP(xB, wid + 4);

#undef PREF
#undef COMP
}

// ---------------- GEMM: out[b,o,m] = sum_t Wb[o,t] * Aout[b,m,t] ----------------
__global__ __launch_bounds__(512) void kgemm(const ushortT* __restrict__ Wb,
                                             const ushortT* __restrict__ Aout,
                                             float* __restrict__ out) {
  __shared__ ushortT At[128 * 40];
  __shared__ ushortT Bt[128 * 40];
  const int b = blockIdx.y;
  const int m0 = blockIdx.x * 128;
  const int tid = threadIdx.x;
  const int w = tid >> 6, l = tid & 63;
  const int ow = (w >> 2) * 64, mw = (w & 3) * 32;
  const int fr = l & 15, fg = l >> 4;
  f32x4 acc[4][2];
  #pragma unroll
  for (int i = 0; i < 4; i++)
    #pragma unroll
    for (int j = 0; j < 2; j++)
      acc[i][j] = (f32x4){0.f, 0.f, 0.f, 0.f};
  const int srow = tid >> 2, sk = (tid & 3) * 8;
  const ushortT* wp = Wb + srow * TT + sk;
  const ushortT* ap = Aout + ((size_t)b * MM + m0 + srow) * TT + sk;
  for (int k0 = 0; k0 < TT; k0 += 32) {
    uint4 wv = *(const uint4*)(wp + k0);
    uint4 av = *(const uint4*)(ap + k0);
    *(uint4*)&At[srow * 40 + sk] = wv;
    *(uint4*)&Bt[srow * 40 + sk] = av;
    __syncthreads();
    short8 a[4], bfrag[2];
    #pragma unroll
    for (int i = 0; i < 4; i++) a[i] = *(short8*)&At[(ow + i * 16 + fr) * 40 + fg * 8];
    #pragma unroll
    for (int j = 0; j < 2; j++) bfrag[j] = *(short8*)&Bt[(mw + j * 16 + fr) * 40 + fg * 8];
    #pragma unroll
    for (int i = 0; i < 4; i++)
      #pragma unroll
      for (int j = 0; j < 2; j++)
        acc[i][j] = __builtin_amdgcn_mfma_f32_16x16x32_bf16(a[i], bfrag[j], acc[i][j], 0, 0, 0);
    __syncthreads();
  }
  #pragma unroll
  for (int i = 0; i < 4; i++)
    #pragma unroll
    for (int j = 0; j < 2; j++)
      #pragma unroll
      for (int r = 0; r < 4; r++) {
        const int o = ow + i * 16 + fg * 4 + r;
        const int m = m0 + mw + j * 16 + fr;
        out[((size_t)b * DOUT + o) * MM + m] = acc[i][j][r];
      }
}

// ---------------- launch ----------------
#define XTB_OFF 0
#define PTS_OFF 33554432
#define AOUT_OFF 67108864
#define WB_OFF 201326592
#define ST_OFF 201850880

extern "C" void kernel_launch(void* const* d_in, const int* in_sizes, int n_in,
                              void* d_out, int out_size, void* d_ws, size_t ws_size,
                              hipStream_t stream) {
  const float* xyz  = (const float*)d_in[0];
  const float* x    = (const float*)d_in[1];
  const float* xyzc = (const float*)d_in[2];
  const int*   idx  = (const int*)d_in[3];
  const float* alpha = (const float*)d_in[4];
  const float* beta  = (const float*)d_in[5];
  const float* nrad  = (const float*)d_in[6];
  const float* w1 = (const float*)d_in[7];
  const float* g1 = (const float*)d_in[8];
  const float* b1 = (const float*)d_in[9];
  const float* w2 = (const float*)d_in[10];
  const float* g2 = (const float*)d_in[11];
  const float* b2 = (const float*)d_in[12];
  const float* w3 = (const float*)d_in[13];
  const float* cvw = (const float*)d_in[14];
  char* ws = (char*)d_ws;
  ushortT* xTb  = (ushortT*)(ws + XTB_OFF);
  float4*  pts4 = (float4*)(ws + PTS_OFF);
  ushortT* Aout = (ushortT*)(ws + AOUT_OFF);
  ushortT* Wb   = (ushortT*)(ws + WB_OFF);
  float*   st   = (float*)(ws + ST_OFF);
  float* out = (float*)d_out;

  hipMemsetAsync(st, 0, 4096, stream);
  kxT<<<dim3(NN / 32, DD / 32, BB), dim3(32, 8), 0, stream>>>(x, xTb);
  kWb<<<dim3(DOUT * TT / 256), 256, 0, stream>>>(cvw, Wb);
  kpassA<<<dim3(MM / 16, BB), 256, 0, stream>>>(xyz, xyzc, idx, w1, st, pts4);
  kS1<<<1, 64, 0, stream>>>(nrad, g1, b1, st);
  kpassB<<<dim3(MM / 16, BB), 256, 0, stream>>>(pts4, alpha, beta, w1, w2, st);
  kS2<<<1, 64, 0, stream>>>(g2, b2, st);
  kF1m<<<dim3(MM / 16, BB), 256, 0, stream>>>(pts4, idx, alpha, beta, w1, w2, w3, st, xTb, Aout);
  kgemm<<<dim3(MM / 128, BB), 512, 0, stream>>>(Wb, Aout, out);
}

// Round 10
// 214.978 us; speedup vs baseline: 1.0989x; 1.0041x over previous
//
#include <hip/hip_runtime.h>
#include <hip/hip_bf16.h>

#define BB 4
#define NN 32768
#define MM 8192
#define KK 16
#define DD 128
#define DOUT 128
#define TT 2048

typedef unsigned short ushortT;
typedef unsigned int uintT;
typedef __attribute__((ext_vector_type(8))) short short8;
typedef __attribute__((ext_vector_type(4))) float f32x4;
typedef __attribute__((ext_vector_type(2))) float f32x2;

__device__ __forceinline__ ushortT f2bf(float f) {
  union { float f; uintT u; } v; v.f = f;
  uintT u = v.u;
  return (ushortT)((u + 0x7FFFu + ((u >> 16) & 1u)) >> 16);
}

// stats layout (floats) in ws
#define ST_MAXD 0
#define ST_E1 16     // [b*32 + o] = sum, [b*32 + 16 + o] = sumsq
#define ST_A1 160
#define ST_B1 224
#define ST_E2 288
#define ST_A2 416
#define ST_B2 480

// ---------------- transpose x (B,D,N) f32 -> xTb (B,N,D) bf16 ----------------
__global__ __launch_bounds__(256) void kxT(const float* __restrict__ x, ushortT* __restrict__ xTb) {
  __shared__ float tile[32][33];
  const int b = blockIdx.z;
  const int n0 = blockIdx.x * 32, d0 = blockIdx.y * 32;
  const int tx = threadIdx.x, ty = threadIdx.y;
  const float* xp = x + (size_t)b * DD * NN;
  #pragma unroll
  for (int i = 0; i < 4; i++)
    tile[ty + i * 8][tx] = xp[(size_t)(d0 + ty + i * 8) * NN + n0 + tx];
  __syncthreads();
  ushortT* op = xTb + (size_t)b * NN * DD;
  #pragma unroll
  for (int i = 0; i < 4; i++)
    op[(size_t)(n0 + ty + i * 8) * DD + d0 + tx] = f2bf(tile[tx][ty + i * 8]);
}

// ---------------- cv_w f32 -> bf16 ----------------
__global__ __launch_bounds__(256) void kWb(const float* __restrict__ cw, ushortT* __restrict__ wb) {
  const int i = blockIdx.x * 256 + threadIdx.x;
  wb[i] = f2bf(cw[i]);
}

// ---------------- pass A: mean_radius + e1 stats + write pts4 ----------------
__global__ __launch_bounds__(256) void kpassA(const float* __restrict__ xyz,
    const float* __restrict__ xyzc, const int* __restrict__ idx,
    const float* __restrict__ w1, float* __restrict__ st, float4* __restrict__ pts4) {
  const int b = blockIdx.y;
  const int tid = threadIdx.x;
  const int mloc = tid >> 4, k = tid & 15;
  const int m = blockIdx.x * 16 + mloc;
  const int gi = (b * MM + m) * KK + k;
  const int n = idx[gi];
  const float cx = xyzc[(b * MM + m) * 3 + 0];
  const float cy = xyzc[(b * MM + m) * 3 + 1];
  const float cz = xyzc[(b * MM + m) * 3 + 2];
  const float* p = xyz + ((size_t)b * NN + n) * 3;
  const float px = p[0] - cx, py = p[1] - cy, pz = p[2] - cz;
  const float dist = sqrtf(px * px + py * py + pz * pz);
  pts4[gi] = (float4){px, py, pz, dist};
  float maxd = dist;
  maxd = fmaxf(maxd, __shfl_xor(maxd, 1));
  maxd = fmaxf(maxd, __shfl_xor(maxd, 2));
  maxd = fmaxf(maxd, __shfl_xor(maxd, 4));
  maxd = fmaxf(maxd, __shfl_xor(maxd, 8));
  __shared__ float red[16];
  __shared__ float wred[4][32];
  if (k == 0) red[mloc] = maxd;
  float vs[16], vq[16];
  #pragma unroll
  for (int o = 0; o < 16; o++) {
    float e = px * w1[3 * o] + py * w1[3 * o + 1] + pz * w1[3 * o + 2];
    vs[o] = e; vq[o] = e * e;
  }
  #pragma unroll
  for (int s = 1; s < 64; s <<= 1) {
    #pragma unroll
    for (int o = 0; o < 16; o++) {
      vs[o] += __shfl_xor(vs[o], s);
      vq[o] += __shfl_xor(vq[o], s);
    }
  }
  const int wv = tid >> 6, lane = tid & 63;
  if (lane == 0) {
    #pragma unroll
    for (int o = 0; o < 16; o++) { wred[wv][o] = vs[o]; wred[wv][16 + o] = vq[o]; }
  }
  __syncthreads();
  if (tid < 32) {
    float a = wred[0][tid] + wred[1][tid] + wred[2][tid] + wred[3][tid];
    atomicAdd(&st[ST_E1 + b * 32 + tid], a);
  }
  if (tid == 0) {
    float s = 0.f;
    #pragma unroll
    for (int i = 0; i < 16; i++) s += red[i];
    atomicAdd(&st[ST_MAXD], s);
  }
}

// ---------------- finalize 1: nr, A1/B1 ----------------
__global__ void kS1(const float* __restrict__ nrad, const float* __restrict__ g1,
                    const float* __restrict__ b1, float* __restrict__ st) {
  const int tid = threadIdx.x;
  if (tid >= 64) return;
  const float meanrad = st[ST_MAXD] / (float)(BB * MM);
  const float nr = nrad[0] * 0.9f + meanrad * 0.1f;
  const int b = tid >> 4, o = tid & 15;
  const float cnt = (float)(MM * KK);
  const float sum = st[ST_E1 + b * 32 + o];
  const float sq  = st[ST_E1 + b * 32 + 16 + o];
  const float mu = sum / cnt;
  float var = sq / cnt - mu * mu; var = fmaxf(var, 0.f);
  const float invs = rsqrtf(var + 1e-5f * nr * nr);
  const float a = invs * g1[o];
  st[ST_A1 + b * 16 + o] = a;
  st[ST_B1 + b * 16 + o] = b1[o] - mu * a;
}

// ---------------- pass B: e2 stats (pure stream from pts4) ----------------
__global__ __launch_bounds__(256) void kpassB(const float4* __restrict__ pts4,
    const float* __restrict__ alpha, const float* __restrict__ beta,
    const float* __restrict__ w1, const float* __restrict__ w2,
    float* __restrict__ st) {
  const int b = blockIdx.y;
  const int tid = threadIdx.x;
  __shared__ float wred[4][32];
  const int gi = b * MM * KK + blockIdx.x * 256 + tid;
  const float4 p4 = pts4[gi];
  const float px = p4.x, py = p4.y, pz = p4.z, dist = p4.w;
  float dwv = 1.f / (1.f + expf(alpha[0] * dist - beta[0]));
  float s = dwv;
  s += __shfl_xor(s, 1); s += __shfl_xor(s, 2); s += __shfl_xor(s, 4); s += __shfl_xor(s, 8);
  s = s + (s == 0.f ? 1.f : 0.f) + 1e-6f;
  dwv = dwv / s * 16.f;
  f32x2 v1[16];
  #pragma unroll
  for (int o = 0; o < 16; o++) {
    float e = px * w1[3 * o] + py * w1[3 * o + 1] + pz * w1[3 * o + 2];
    float v = e * st[ST_A1 + b * 16 + o] + st[ST_B1 + b * 16 + o];
    v = fmaxf(v, 0.f);
    float t = v * dwv;
    t = fmaxf(t, __shfl_xor(t, 1)); t = fmaxf(t, __shfl_xor(t, 2));
    t = fmaxf(t, __shfl_xor(t, 4)); t = fmaxf(t, __shfl_xor(t, 8));
    if (o & 1) { v1[o >> 1].y = v; v1[8 + (o >> 1)].y = t; }
    else       { v1[o >> 1].x = v; v1[8 + (o >> 1)].x = t; }
  }
  float vs[16], vq[16];
  #pragma unroll
  for (int o = 0; o < 16; o++) {
    f32x2 acc = {0.f, 0.f};
    #pragma unroll
    for (int cp = 0; cp < 16; cp++) {
      const f32x2 wv = *(const f32x2*)(w2 + o * 32 + 2 * cp);
      acc += v1[cp] * wv;
    }
    const float e = acc.x + acc.y;
    vs[o] = e; vq[o] = e * e;
  }
  #pragma unroll
  for (int s2 = 1; s2 < 64; s2 <<= 1) {
    #pragma unroll
    for (int o = 0; o < 16; o++) {
      vs[o] += __shfl_xor(vs[o], s2);
      vq[o] += __shfl_xor(vq[o], s2);
    }
  }
  const int wv = tid >> 6, lane = tid & 63;
  if (lane == 0) {
    #pragma unroll
    for (int o = 0; o < 16; o++) { wred[wv][o] = vs[o]; wred[wv][16 + o] = vq[o]; }
  }
  __syncthreads();
  if (tid < 32) {
    float a = wred[0][tid] + wred[1][tid] + wred[2][tid] + wred[3][tid];
    atomicAdd(&st[ST_E2 + b * 32 + tid], a);
  }
}

// ---------------- finalize 2: A2/B2 ----------------
__global__ void kS2(const float* __restrict__ g2, const float* __restrict__ b2,
                    float* __restrict__ st) {
  const int tid = threadIdx.x;
  if (tid >= 64) return;
  const int b = tid >> 4, o = tid & 15;
  const float cnt = (float)(MM * KK);
  const float sum = st[ST_E2 + b * 32 + o];
  const float sq  = st[ST_E2 + b * 32 + 16 + o];
  const float mu = sum / cnt;
  float var = sq / cnt - mu * mu; var = fmaxf(var, 0.f);
  const float invs = rsqrtf(var + 1e-5f);
  const float a = invs * g2[o];
  st[ST_A2 + b * 16 + o] = a;
  st[ST_B2 + b * 16 + o] = b2[o] - mu * a;
}

// ---------------- kF1m: fused phase1 + m-pair gather contraction, 256 thr ----
// R10: R9's spill (WRITE 185MB vs 134, occ 30.9%) came from issuing PREF(xA)
// BEFORE layers 2/3 -- the 32-reg xA buffer was live across the ~90-reg
// layer-2/3 section, pushing peak past the (256,3)=170 budget. Fix: issue
// PREF(xA) AFTER the mat3s store, right before the barrier. xA never overlaps
// the phase-1 temps; peak live = COMP region ~148 regs < 170. Cost: first
// gather fill (~700cy) exposed once per block at the barrier (~1us aggregate).
// Verification: WRITE_SIZE must revert to ~134MB.
__global__ __launch_bounds__(256, 3) void kF1m(const float4* __restrict__ pts4,
    const int* __restrict__ idx,
    const float* __restrict__ alpha, const float* __restrict__ beta,
    const float* __restrict__ w1, const float* __restrict__ w2, const float* __restrict__ w3,
    const float* __restrict__ st, const ushortT* __restrict__ xTb, ushortT* __restrict__ Aout) {
  __shared__ float mat3s[16 * 256];   // 16KB
  const int b = blockIdx.y;
  const int tid = threadIdx.x;
  const int m0 = blockIdx.x * 16;

  // ---- phase 1: thread = (mloc = tid>>4, k1 = tid&15) ----
  const int mloc = tid >> 4, k1 = tid & 15;
  const int gi = (b * MM + m0) * KK + tid;
  const float4 p4 = pts4[gi];
  const float px = p4.x, py = p4.y, pz = p4.z, dist = p4.w;
  float dwv = 1.f / (1.f + expf(alpha[0] * dist - beta[0]));
  {
    float s = dwv;
    s += __shfl_xor(s, 1); s += __shfl_xor(s, 2); s += __shfl_xor(s, 4); s += __shfl_xor(s, 8);
    s = s + (s == 0.f ? 1.f : 0.f) + 1e-6f;
    dwv = dwv / s * 16.f;
  }
  // layer 1 -> v1 pairs
  f32x2 v1[16];
  #pragma unroll
  for (int o = 0; o < 16; o++) {
    float e = px * w1[3 * o] + py * w1[3 * o + 1] + pz * w1[3 * o + 2];
    float v = e * st[ST_A1 + b * 16 + o] + st[ST_B1 + b * 16 + o];
    v = fmaxf(v, 0.f);
    float t = v * dwv;
    t = fmaxf(t, __shfl_xor(t, 1)); t = fmaxf(t, __shfl_xor(t, 2));
    t = fmaxf(t, __shfl_xor(t, 4)); t = fmaxf(t, __shfl_xor(t, 8));
    if (o & 1) { v1[o >> 1].y = v; v1[8 + (o >> 1)].y = t; }
    else       { v1[o >> 1].x = v; v1[8 + (o >> 1)].x = t; }
  }

  // layers 2+3 (weights via s_load from global)
  {
    float in2[16];
    #pragma unroll
    for (int o = 0; o < 16; o++) {
      f32x2 acc = {0.f, 0.f};
      #pragma unroll
      for (int cp = 0; cp < 16; cp++) {
        const f32x2 wv = *(const f32x2*)(w2 + o * 32 + 2 * cp);
        acc += v1[cp] * wv;
      }
      float v = (acc.x + acc.y) * st[ST_A2 + b * 16 + o] + st[ST_B2 + b * 16 + o];
      in2[o] = fmaxf(v, 0.f);
    }
    f32x2 v2[16];
    #pragma unroll
    for (int o = 0; o < 16; o++) {
      float t = in2[o] * dwv;
      t = fmaxf(t, __shfl_xor(t, 1)); t = fmaxf(t, __shfl_xor(t, 2));
      t = fmaxf(t, __shfl_xor(t, 4)); t = fmaxf(t, __shfl_xor(t, 8));
      if (o & 1) { v2[o >> 1].y = in2[o]; v2[8 + (o >> 1)].y = t; }
      else       { v2[o >> 1].x = in2[o]; v2[8 + (o >> 1)].x = t; }
    }
    float m3v[16];
    #pragma unroll
    for (int j = 0; j < 16; j++) {
      f32x2 acc = {0.f, 0.f};
      #pragma unroll
      for (int cp = 0; cp < 16; cp++) {
        const f32x2 wv = *(const f32x2*)(w3 + j * 32 + 2 * cp);
        acc += v2[cp] * wv;
      }
      m3v[j] = fmaxf(acc.x + acc.y, 0.f) * dwv;
    }
    const int swz1 = (k1 ^ (k1 >> 2)) & 3;
    float* m3w = &mat3s[mloc * 256 + k1 * 16];
    #pragma unroll
    for (int q = 0; q < 4; q++)
      *(f32x4*)(m3w + ((q ^ swz1) << 2)) =
          (f32x4){m3v[4 * q], m3v[4 * q + 1], m3v[4 * q + 2], m3v[4 * q + 3]};
  }

  // ---- phase-2 geometry + prefetch (AFTER phase-1 temps die) ----
  const int wid = __builtin_amdgcn_readfirstlane(tid >> 6);
  const int lane = tid & 63;
  const int mh = lane >> 5;
  const int dq = lane & 31;
  const int d0 = dq * 4;
  const ushortT* xb = xTb + (size_t)b * NN * DD + d0;

  uint2 xA[16], xB[16];

#define PREF(dst, p) do {                                                  \
    const int* ib0 = idx + ((b * MM + m0 + (p) * 2) << 4);                 \
    const int* ib1 = ib0 + 16;                                             \
    _Pragma("unroll")                                                      \
    for (int t = 0; t < 16; t++) {                                         \
      const int ke = ib0[t], ko = ib1[t];                                  \
      const uintT nn = (uintT)(mh ? ko : ke);                              \
      (dst)[t] = *(const uint2*)(xb + ((size_t)nn << 7));                  \
    }                                                                      \
  } while (0)

  PREF(xA, wid);    // issued just before barrier; drains with the barrier
  __syncthreads();  // mat3s ready

#define COMP(src, p) do {                                                  \
    const float* m3base = &mat3s[((p) * 2 + mh) * 256];                    \
    f32x2 a2[4][8];                                                        \
    _Pragma("unroll")                                                      \
    for (int d = 0; d < 4; d++)                                            \
      _Pragma("unroll")                                                    \
      for (int c = 0; c < 8; c++) a2[d][c] = (f32x2){0.f, 0.f};            \
    _Pragma("unroll")                                                      \
    for (int t = 0; t < 16; t++) {                                         \
      const int sw = (t ^ (t >> 2)) & 3;                                   \
      const uint2 xv = (src)[t];                                           \
      const f32x4 mq0 = *(const f32x4*)(m3base + t * 16 + ((0 ^ sw) << 2));\
      const f32x4 mq1 = *(const f32x4*)(m3base + t * 16 + ((1 ^ sw) << 2));\
      const f32x4 mq2 = *(const f32x4*)(m3base + t * 16 + ((2 ^ sw) << 2));\
      const f32x4 mq3 = *(const f32x4*)(m3base + t * 16 + ((3 ^ sw) << 2));\
      float xs[4];                                                         \
      xs[0] = __uint_as_float(xv.x << 16);                                 \
      xs[1] = __uint_as_float(xv.x & 0xFFFF0000u);                         \
      xs[2] = __uint_as_float(xv.y << 16);                                 \
      xs[3] = __uint_as_float(xv.y & 0xFFFF0000u);                         \
      f32x2 mp[8];                                                         \
      mp[0] = mq0.lo; mp[1] = mq0.hi;                                      \
      mp[2] = mq1.lo; mp[3] = mq1.hi;                                      \
      mp[4] = mq2.lo; mp[5] = mq2.hi;                                      \
      mp[6] = mq3.lo; mp[7] = mq3.hi;                                      \
      _Pragma("unroll")                                                    \
      for (int d = 0; d < 4; d++) {                                        \
        const float xd = xs[d];                                            \
        _Pragma("unroll")                                                  \
        for (int c = 0; c < 8; c++)                                        \
          a2[d][c] += mp[c] * xd;                                          \
      }                                                                    \
    }                                                                      \
    ushortT* aop = Aout + ((size_t)b * MM + m0 + (p) * 2 + mh) * TT + d0 * 16; \
    _Pragma("unroll")                                                      \
    for (int d = 0; d < 4; d++) {                                          \
      uintT u[8];                                                          \
      _Pragma("unroll")                                                    \
      for (int c = 0; c < 8; c++)                                          \
        u[c] = (uintT)f2bf(a2[d][c].x) | ((uintT)f2bf(a2[d][c].y) << 16);  \
      *(uint4*)(aop + d * 16)     = (uint4){u[0], u[1], u[2], u[3]};       \
      *(uint4*)(aop + d * 16 + 8) = (uint4){u[4], u[5], u[6], u[7]};       \
    }                                                                      \
  } while (0)

  PREF(xB, wid + 4);
  COMP(xA, wid);
  COMP(xB, wid + 4);

#undef PREF
#undef COMP
}

// ---------------- GEMM: out[b,o,m] = sum_t Wb[o,t] * Aout[b,m,t] ----------------
__global__ __launch_bounds__(512) void kgemm(const ushortT* __restrict__ Wb,
                                             const ushortT* __restrict__ Aout,
                                             float* __restrict__ out) {
  __shared__ ushortT At[128 * 40];
  __shared__ ushortT Bt[128 * 40];
  const int b = blockIdx.y;
  const int m0 = blockIdx.x * 128;
  const int tid = threadIdx.x;
  const int w = tid >> 6, l = tid & 63;
  const int ow = (w >> 2) * 64, mw = (w & 3) * 32;
  const int fr = l & 15, fg = l >> 4;
  f32x4 acc[4][2];
  #pragma unroll
  for (int i = 0; i < 4; i++)
    #pragma unroll
    for (int j = 0; j < 2; j++)
      acc[i][j] = (f32x4){0.f, 0.f, 0.f, 0.f};
  const int srow = tid >> 2, sk = (tid & 3) * 8;
  const ushortT* wp = Wb + srow * TT + sk;
  const ushortT* ap = Aout + ((size_t)b * MM + m0 + srow) * TT + sk;
  for (int k0 = 0; k0 < TT; k0 += 32) {
    uint4 wv = *(const uint4*)(wp + k0);
    uint4 av = *(const uint4*)(ap + k0);
    *(uint4*)&At[srow * 40 + sk] = wv;
    *(uint4*)&Bt[srow * 40 + sk] = av;
    __syncthreads();
    short8 a[4], bfrag[2];
    #pragma unroll
    for (int i = 0; i < 4; i++) a[i] = *(short8*)&At[(ow + i * 16 + fr) * 40 + fg * 8];
    #pragma unroll
    for (int j = 0; j < 2; j++) bfrag[j] = *(short8*)&Bt[(mw + j * 16 + fr) * 40 + fg * 8];
    #pragma unroll
    for (int i = 0; i < 4; i++)
      #pragma unroll
      for (int j = 0; j < 2; j++)
        acc[i][j] = __builtin_amdgcn_mfma_f32_16x16x32_bf16(a[i], bfrag[j], acc[i][j], 0, 0, 0);
    __syncthreads();
  }
  #pragma unroll
  for (int i = 0; i < 4; i++)
    #pragma unroll
    for (int j = 0; j < 2; j++)
      #pragma unroll
      for (int r = 0; r < 4; r++) {
        const int o = ow + i * 16 + fg * 4 + r;
        const int m = m0 + mw + j * 16 + fr;
        out[((size_t)b * DOUT + o) * MM + m] = acc[i][j][r];
      }
}

// ---------------- launch ----------------
#define XTB_OFF 0
#define PTS_OFF 33554432
#define AOUT_OFF 67108864
#define WB_OFF 201326592
#define ST_OFF 201850880

extern "C" void kernel_launch(void* const* d_in, const int* in_sizes, int n_in,
                              void* d_out, int out_size, void* d_ws, size_t ws_size,
                              hipStream_t stream) {
  const float* xyz  = (const float*)d_in[0];
  const float* x    = (const float*)d_in[1];
  const float* xyzc = (const float*)d_in[2];
  const int*   idx  = (const int*)d_in[3];
  const float* alpha = (const float*)d_in[4];
  const float* beta  = (const float*)d_in[5];
  const float* nrad  = (const float*)d_in[6];
  const float* w1 = (const float*)d_in[7];
  const float* g1 = (const float*)d_in[8];
  const float* b1 = (const float*)d_in[9];
  const float* w2 = (const float*)d_in[10];
  const float* g2 = (const float*)d_in[11];
  const float* b2 = (const float*)d_in[12];
  const float* w3 = (const float*)d_in[13];
  const float* cvw = (const float*)d_in[14];
  char* ws = (char*)d_ws;
  ushortT* xTb  = (ushortT*)(ws + XTB_OFF);
  float4*  pts4 = (float4*)(ws + PTS_OFF);
  ushortT* Aout = (ushortT*)(ws + AOUT_OFF);
  ushortT* Wb   = (ushortT*)(ws + WB_OFF);
  float*   st   = (float*)(ws + ST_OFF);
  float* out = (float*)d_out;

  hipMemsetAsync(st, 0, 4096, stream);
  kxT<<<dim3(NN / 32, DD / 32, BB), dim3(32, 8), 0, stream>>>(x, xTb);
  kWb<<<dim3(DOUT * TT / 256), 256, 0, stream>>>(cvw, Wb);
  kpassA<<<dim3(MM / 16, BB), 256, 0, stream>>>(xyz, xyzc, idx, w1, st, pts4);
  kS1<<<1, 64, 0, stream>>>(nrad, g1, b1, st);
  kpassB<<<dim3(MM / 16, BB), 256, 0, stream>>>(pts4, alpha, beta, w1, w2, st);
  kS2<<<1, 64, 0, stream>>>(g2, b2, st);
  kF1m<<<dim3(MM / 16, BB), 256, 0, stream>>>(pts4, idx, alpha, beta, w1, w2, w3, st, xTb, Aout);
  kgemm<<<dim3(MM / 128, BB), 512, 0, stream>>>(Wb, Aout, out);
}

// Round 11
// 213.151 us; speedup vs baseline: 1.1083x; 1.0086x over previous
//
#include <hip/hip_runtime.h>
#include <hip/hip_bf16.h>

#define BB 4
#define NN 32768
#define MM 8192
#define KK 16
#define DD 128
#define DOUT 128
#define TT 2048

typedef unsigned short ushortT;
typedef unsigned int uintT;
typedef __attribute__((ext_vector_type(8))) short short8;
typedef __attribute__((ext_vector_type(4))) float f32x4;
typedef __attribute__((ext_vector_type(2))) float f32x2;

__device__ __forceinline__ ushortT f2bf(float f) {
  union { float f; uintT u; } v; v.f = f;
  uintT u = v.u;
  return (ushortT)((u + 0x7FFFu + ((u >> 16) & 1u)) >> 16);
}

// stats layout (floats) in ws
#define ST_MAXD 0
#define ST_E1 16     // [b*32 + o] = sum, [b*32 + 16 + o] = sumsq
#define ST_A1 160
#define ST_B1 224
#define ST_E2 288
#define ST_A2 416
#define ST_B2 480

// ---------------- transpose x (B,D,N) f32 -> xTb (B,N,D) bf16 ----------------
__global__ __launch_bounds__(256) void kxT(const float* __restrict__ x, ushortT* __restrict__ xTb) {
  __shared__ float tile[32][33];
  const int b = blockIdx.z;
  const int n0 = blockIdx.x * 32, d0 = blockIdx.y * 32;
  const int tx = threadIdx.x, ty = threadIdx.y;
  const float* xp = x + (size_t)b * DD * NN;
  #pragma unroll
  for (int i = 0; i < 4; i++)
    tile[ty + i * 8][tx] = xp[(size_t)(d0 + ty + i * 8) * NN + n0 + tx];
  __syncthreads();
  ushortT* op = xTb + (size_t)b * NN * DD;
  #pragma unroll
  for (int i = 0; i < 4; i++)
    op[(size_t)(n0 + ty + i * 8) * DD + d0 + tx] = f2bf(tile[tx][ty + i * 8]);
}

// ---------------- cv_w f32 -> bf16 ----------------
__global__ __launch_bounds__(256) void kWb(const float* __restrict__ cw, ushortT* __restrict__ wb) {
  const int i = blockIdx.x * 256 + threadIdx.x;
  wb[i] = f2bf(cw[i]);
}

// ---------------- pass A: mean_radius + e1 stats + write pts4 ----------------
__global__ __launch_bounds__(256) void kpassA(const float* __restrict__ xyz,
    const float* __restrict__ xyzc, const int* __restrict__ idx,
    const float* __restrict__ w1, float* __restrict__ st, float4* __restrict__ pts4) {
  const int b = blockIdx.y;
  const int tid = threadIdx.x;
  const int mloc = tid >> 4, k = tid & 15;
  const int m = blockIdx.x * 16 + mloc;
  const int gi = (b * MM + m) * KK + k;
  const int n = idx[gi];
  const float cx = xyzc[(b * MM + m) * 3 + 0];
  const float cy = xyzc[(b * MM + m) * 3 + 1];
  const float cz = xyzc[(b * MM + m) * 3 + 2];
  const float* p = xyz + ((size_t)b * NN + n) * 3;
  const float px = p[0] - cx, py = p[1] - cy, pz = p[2] - cz;
  const float dist = sqrtf(px * px + py * py + pz * pz);
  pts4[gi] = (float4){px, py, pz, dist};
  float maxd = dist;
  maxd = fmaxf(maxd, __shfl_xor(maxd, 1));
  maxd = fmaxf(maxd, __shfl_xor(maxd, 2));
  maxd = fmaxf(maxd, __shfl_xor(maxd, 4));
  maxd = fmaxf(maxd, __shfl_xor(maxd, 8));
  __shared__ float red[16];
  __shared__ float wred[4][32];
  if (k == 0) red[mloc] = maxd;
  float vs[16], vq[16];
  #pragma unroll
  for (int o = 0; o < 16; o++) {
    float e = px * w1[3 * o] + py * w1[3 * o + 1] + pz * w1[3 * o + 2];
    vs[o] = e; vq[o] = e * e;
  }
  #pragma unroll
  for (int s = 1; s < 64; s <<= 1) {
    #pragma unroll
    for (int o = 0; o < 16; o++) {
      vs[o] += __shfl_xor(vs[o], s);
      vq[o] += __shfl_xor(vq[o], s);
    }
  }
  const int wv = tid >> 6, lane = tid & 63;
  if (lane == 0) {
    #pragma unroll
    for (int o = 0; o < 16; o++) { wred[wv][o] = vs[o]; wred[wv][16 + o] = vq[o]; }
  }
  __syncthreads();
  if (tid < 32) {
    float a = wred[0][tid] + wred[1][tid] + wred[2][tid] + wred[3][tid];
    atomicAdd(&st[ST_E1 + b * 32 + tid], a);
  }
  if (tid == 0) {
    float s = 0.f;
    #pragma unroll
    for (int i = 0; i < 16; i++) s += red[i];
    atomicAdd(&st[ST_MAXD], s);
  }
}

// ---------------- finalize 1: nr, A1/B1 ----------------
__global__ void kS1(const float* __restrict__ nrad, const float* __restrict__ g1,
                    const float* __restrict__ b1, float* __restrict__ st) {
  const int tid = threadIdx.x;
  if (tid >= 64) return;
  const float meanrad = st[ST_MAXD] / (float)(BB * MM);
  const float nr = nrad[0] * 0.9f + meanrad * 0.1f;
  const int b = tid >> 4, o = tid & 15;
  const float cnt = (float)(MM * KK);
  const float sum = st[ST_E1 + b * 32 + o];
  const float sq  = st[ST_E1 + b * 32 + 16 + o];
  const float mu = sum / cnt;
  float var = sq / cnt - mu * mu; var = fmaxf(var, 0.f);
  const float invs = rsqrtf(var + 1e-5f * nr * nr);
  const float a = invs * g1[o];
  st[ST_A1 + b * 16 + o] = a;
  st[ST_B1 + b * 16 + o] = b1[o] - mu * a;
}

// ---------------- pass B: e2 stats (pure stream from pts4) ----------------
__global__ __launch_bounds__(256) void kpassB(const float4* __restrict__ pts4,
    const float* __restrict__ alpha, const float* __restrict__ beta,
    const float* __restrict__ w1, const float* __restrict__ w2,
    float* __restrict__ st) {
  const int b = blockIdx.y;
  const int tid = threadIdx.x;
  __shared__ float wred[4][32];
  const int gi = b * MM * KK + blockIdx.x * 256 + tid;
  const float4 p4 = pts4[gi];
  const float px = p4.x, py = p4.y, pz = p4.z, dist = p4.w;
  float dwv = 1.f / (1.f + expf(alpha[0] * dist - beta[0]));
  float s = dwv;
  s += __shfl_xor(s, 1); s += __shfl_xor(s, 2); s += __shfl_xor(s, 4); s += __shfl_xor(s, 8);
  s = s + (s == 0.f ? 1.f : 0.f) + 1e-6f;
  dwv = dwv / s * 16.f;
  f32x2 v1[16];
  #pragma unroll
  for (int o = 0; o < 16; o++) {
    float e = px * w1[3 * o] + py * w1[3 * o + 1] + pz * w1[3 * o + 2];
    float v = e * st[ST_A1 + b * 16 + o] + st[ST_B1 + b * 16 + o];
    v = fmaxf(v, 0.f);
    float t = v * dwv;
    t = fmaxf(t, __shfl_xor(t, 1)); t = fmaxf(t, __shfl_xor(t, 2));
    t = fmaxf(t, __shfl_xor(t, 4)); t = fmaxf(t, __shfl_xor(t, 8));
    if (o & 1) { v1[o >> 1].y = v; v1[8 + (o >> 1)].y = t; }
    else       { v1[o >> 1].x = v; v1[8 + (o >> 1)].x = t; }
  }
  float vs[16], vq[16];
  #pragma unroll
  for (int o = 0; o < 16; o++) {
    f32x2 acc = {0.f, 0.f};
    #pragma unroll
    for (int cp = 0; cp < 16; cp++) {
      const f32x2 wv = *(const f32x2*)(w2 + o * 32 + 2 * cp);
      acc += v1[cp] * wv;
    }
    const float e = acc.x + acc.y;
    vs[o] = e; vq[o] = e * e;
  }
  #pragma unroll
  for (int s2 = 1; s2 < 64; s2 <<= 1) {
    #pragma unroll
    for (int o = 0; o < 16; o++) {
      vs[o] += __shfl_xor(vs[o], s2);
      vq[o] += __shfl_xor(vq[o], s2);
    }
  }
  const int wv = tid >> 6, lane = tid & 63;
  if (lane == 0) {
    #pragma unroll
    for (int o = 0; o < 16; o++) { wred[wv][o] = vs[o]; wred[wv][16 + o] = vq[o]; }
  }
  __syncthreads();
  if (tid < 32) {
    float a = wred[0][tid] + wred[1][tid] + wred[2][tid] + wred[3][tid];
    atomicAdd(&st[ST_E2 + b * 32 + tid], a);
  }
}

// ---------------- finalize 2: A2/B2 ----------------
__global__ void kS2(const float* __restrict__ g2, const float* __restrict__ b2,
                    float* __restrict__ st) {
  const int tid = threadIdx.x;
  if (tid >= 64) return;
  const int b = tid >> 4, o = tid & 15;
  const float cnt = (float)(MM * KK);
  const float sum = st[ST_E2 + b * 32 + o];
  const float sq  = st[ST_E2 + b * 32 + 16 + o];
  const float mu = sum / cnt;
  float var = sq / cnt - mu * mu; var = fmaxf(var, 0.f);
  const float invs = rsqrtf(var + 1e-5f);
  const float a = invs * g2[o];
  st[ST_A2 + b * 16 + o] = a;
  st[ST_B2 + b * 16 + o] = b2[o] - mu * a;
}

// ---------------- kF1m: fused phase1 + m-pair gather contraction, 256 thr ----
// R11: R10's source-order fix was a no-op -- the scheduler HOISTED the PREF
// loads back over phase 1 (no dependence), recreating R9's liveness overlap
// and spill (WRITE still 177-187MB). Two co-fixes: (1) SINGLE gather buffer
// (xA only, sequential groups) -- even a hoisted 32-reg buffer peaks at
// ~150 < 170 budget, so the spill becomes impossible rather than
// scheduler-dependent. Group-2 fill exposure ~600cy/wave is hidden by
// 12-wave TLP (~2us aggregate). (2) sched_barrier(0) pins PREF issue after
// phase-1 anyway. Verification: WRITE_SIZE must be ~134MB.
__global__ __launch_bounds__(256, 3) void kF1m(const float4* __restrict__ pts4,
    const int* __restrict__ idx,
    const float* __restrict__ alpha, const float* __restrict__ beta,
    const float* __restrict__ w1, const float* __restrict__ w2, const float* __restrict__ w3,
    const float* __restrict__ st, const ushortT* __restrict__ xTb, ushortT* __restrict__ Aout) {
  __shared__ float mat3s[16 * 256];   // 16KB
  const int b = blockIdx.y;
  const int tid = threadIdx.x;
  const int m0 = blockIdx.x * 16;

  // ---- phase 1: thread = (mloc = tid>>4, k1 = tid&15) ----
  const int mloc = tid >> 4, k1 = tid & 15;
  const int gi = (b * MM + m0) * KK + tid;
  const float4 p4 = pts4[gi];
  const float px = p4.x, py = p4.y, pz = p4.z, dist = p4.w;
  float dwv = 1.f / (1.f + expf(alpha[0] * dist - beta[0]));
  {
    float s = dwv;
    s += __shfl_xor(s, 1); s += __shfl_xor(s, 2); s += __shfl_xor(s, 4); s += __shfl_xor(s, 8);
    s = s + (s == 0.f ? 1.f : 0.f) + 1e-6f;
    dwv = dwv / s * 16.f;
  }
  // layer 1 -> v1 pairs
  f32x2 v1[16];
  #pragma unroll
  for (int o = 0; o < 16; o++) {
    float e = px * w1[3 * o] + py * w1[3 * o + 1] + pz * w1[3 * o + 2];
    float v = e * st[ST_A1 + b * 16 + o] + st[ST_B1 + b * 16 + o];
    v = fmaxf(v, 0.f);
    float t = v * dwv;
    t = fmaxf(t, __shfl_xor(t, 1)); t = fmaxf(t, __shfl_xor(t, 2));
    t = fmaxf(t, __shfl_xor(t, 4)); t = fmaxf(t, __shfl_xor(t, 8));
    if (o & 1) { v1[o >> 1].y = v; v1[8 + (o >> 1)].y = t; }
    else       { v1[o >> 1].x = v; v1[8 + (o >> 1)].x = t; }
  }

  // layers 2+3 (weights via s_load from global)
  {
    float in2[16];
    #pragma unroll
    for (int o = 0; o < 16; o++) {
      f32x2 acc = {0.f, 0.f};
      #pragma unroll
      for (int cp = 0; cp < 16; cp++) {
        const f32x2 wv = *(const f32x2*)(w2 + o * 32 + 2 * cp);
        acc += v1[cp] * wv;
      }
      float v = (acc.x + acc.y) * st[ST_A2 + b * 16 + o] + st[ST_B2 + b * 16 + o];
      in2[o] = fmaxf(v, 0.f);
    }
    f32x2 v2[16];
    #pragma unroll
    for (int o = 0; o < 16; o++) {
      float t = in2[o] * dwv;
      t = fmaxf(t, __shfl_xor(t, 1)); t = fmaxf(t, __shfl_xor(t, 2));
      t = fmaxf(t, __shfl_xor(t, 4)); t = fmaxf(t, __shfl_xor(t, 8));
      if (o & 1) { v2[o >> 1].y = in2[o]; v2[8 + (o >> 1)].y = t; }
      else       { v2[o >> 1].x = in2[o]; v2[8 + (o >> 1)].x = t; }
    }
    float m3v[16];
    #pragma unroll
    for (int j = 0; j < 16; j++) {
      f32x2 acc = {0.f, 0.f};
      #pragma unroll
      for (int cp = 0; cp < 16; cp++) {
        const f32x2 wv = *(const f32x2*)(w3 + j * 32 + 2 * cp);
        acc += v2[cp] * wv;
      }
      m3v[j] = fmaxf(acc.x + acc.y, 0.f) * dwv;
    }
    const int swz1 = (k1 ^ (k1 >> 2)) & 3;
    float* m3w = &mat3s[mloc * 256 + k1 * 16];
    #pragma unroll
    for (int q = 0; q < 4; q++)
      *(f32x4*)(m3w + ((q ^ swz1) << 2)) =
          (f32x4){m3v[4 * q], m3v[4 * q + 1], m3v[4 * q + 2], m3v[4 * q + 3]};
  }

  // ---- phase-2 geometry + single-buffer prefetch ----
  const int wid = __builtin_amdgcn_readfirstlane(tid >> 6);
  const int lane = tid & 63;
  const int mh = lane >> 5;
  const int dq = lane & 31;
  const int d0 = dq * 4;
  const ushortT* xb = xTb + (size_t)b * NN * DD + d0;

  uint2 xA[16];

#define PREF(dst, p) do {                                                  \
    const int* ib0 = idx + ((b * MM + m0 + (p) * 2) << 4);                 \
    const int* ib1 = ib0 + 16;                                             \
    _Pragma("unroll")                                                      \
    for (int t = 0; t < 16; t++) {                                         \
      const int ke = ib0[t], ko = ib1[t];                                  \
      const uintT nn = (uintT)(mh ? ko : ke);                              \
      (dst)[t] = *(const uint2*)(xb + ((size_t)nn << 7));                  \
    }                                                                      \
  } while (0)

  __builtin_amdgcn_sched_barrier(0);  // pin PREF after phase-1 (no hoist)
  PREF(xA, wid);    // drains with the barrier
  __syncthreads();  // mat3s ready

#define COMP(src, p) do {                                                  \
    const float* m3base = &mat3s[((p) * 2 + mh) * 256];                    \
    f32x2 a2[4][8];                                                        \
    _Pragma("unroll")                                                      \
    for (int d = 0; d < 4; d++)                                            \
      _Pragma("unroll")                                                    \
      for (int c = 0; c < 8; c++) a2[d][c] = (f32x2){0.f, 0.f};            \
    _Pragma("unroll")                                                      \
    for (int t = 0; t < 16; t++) {                                         \
      const int sw = (t ^ (t >> 2)) & 3;                                   \
      const uint2 xv = (src)[t];                                           \
      const f32x4 mq0 = *(const f32x4*)(m3base + t * 16 + ((0 ^ sw) << 2));\
      const f32x4 mq1 = *(const f32x4*)(m3base + t * 16 + ((1 ^ sw) << 2));\
      const f32x4 mq2 = *(const f32x4*)(m3base + t * 16 + ((2 ^ sw) << 2));\
      const f32x4 mq3 = *(const f32x4*)(m3base + t * 16 + ((3 ^ sw) << 2));\
      float xs[4];                                                         \
      xs[0] = __uint_as_float(xv.x << 16);                                 \
      xs[1] = __uint_as_float(xv.x & 0xFFFF0000u);                         \
      xs[2] = __uint_as_float(xv.y << 16);                                 \
      xs[3] = __uint_as_float(xv.y & 0xFFFF0000u);                         \
      f32x2 mp[8];                                                         \
      mp[0] = mq0.lo; mp[1] = mq0.hi;                                      \
      mp[2] = mq1.lo; mp[3] = mq1.hi;                                      \
      mp[4] = mq2.lo; mp[5] = mq2.hi;                                      \
      mp[6] = mq3.lo; mp[7] = mq3.hi;                                      \
      _Pragma("unroll")                                                    \
      for (int d = 0; d < 4; d++) {                                        \
        const float xd = xs[d];                                            \
        _Pragma("unroll")                                                  \
        for (int c = 0; c < 8; c++)                                        \
          a2[d][c] += mp[c] * xd;                                          \
      }                                                                    \
    }                                                                      \
    ushortT* aop = Aout + ((size_t)b * MM + m0 + (p) * 2 + mh) * TT + d0 * 16; \
    _Pragma("unroll")                                                      \
    for (int d = 0; d < 4; d++) {                                          \
      uintT u[8];                                                          \
      _Pragma("unroll")                                                    \
      for (int c = 0; c < 8; c++)                                          \
        u[c] = (uintT)f2bf(a2[d][c].x) | ((uintT)f2bf(a2[d][c].y) << 16);  \
      *(uint4*)(aop + d * 16)     = (uint4){u[0], u[1], u[2], u[3]};       \
      *(uint4*)(aop + d * 16 + 8) = (uint4){u[4], u[5], u[6], u[7]};       \
    }                                                                      \
  } while (0)

  COMP(xA, wid);
  PREF(xA, wid + 4);
  COMP(xA, wid + 4);

#undef PREF
#undef COMP
}

// ---------------- GEMM: out[b,o,m] = sum_t Wb[o,t] * Aout[b,m,t] ----------------
__global__ __launch_bounds__(512) void kgemm(const ushortT* __restrict__ Wb,
                                             const ushortT* __restrict__ Aout,
                                             float* __restrict__ out) {
  __shared__ ushortT At[128 * 40];
  __shared__ ushortT Bt[128 * 40];
  const int b = blockIdx.y;
  const int m0 = blockIdx.x * 128;
  const int tid = threadIdx.x;
  const int w = tid >> 6, l = tid & 63;
  const int ow = (w >> 2) * 64, mw = (w & 3) * 32;
  const int fr = l & 15, fg = l >> 4;
  f32x4 acc[4][2];
  #pragma unroll
  for (int i = 0; i < 4; i++)
    #pragma unroll
    for (int j = 0; j < 2; j++)
      acc[i][j] = (f32x4){0.f, 0.f, 0.f, 0.f};
  const int srow = tid >> 2, sk = (tid & 3) * 8;
  const ushortT* wp = Wb + srow * TT + sk;
  const ushortT* ap = Aout + ((size_t)b * MM + m0 + srow) * TT + sk;
  for (int k0 = 0; k0 < TT; k0 += 32) {
    uint4 wv = *(const uint4*)(wp + k0);
    uint4 av = *(const uint4*)(ap + k0);
    *(uint4*)&At[srow * 40 + sk] = wv;
    *(uint4*)&Bt[srow * 40 + sk] = av;
    __syncthreads();
    short8 a[4], bfrag[2];
    #pragma unroll
    for (int i = 0; i < 4; i++) a[i] = *(short8*)&At[(ow + i * 16 + fr) * 40 + fg * 8];
    #pragma unroll
    for (int j = 0; j < 2; j++) bfrag[j] = *(short8*)&Bt[(mw + j * 16 + fr) * 40 + fg * 8];
    #pragma unroll
    for (int i = 0; i < 4; i++)
      #pragma unroll
      for (int j = 0; j < 2; j++)
        acc[i][j] = __builtin_amdgcn_mfma_f32_16x16x32_bf16(a[i], bfrag[j], acc[i][j], 0, 0, 0);
    __syncthreads();
  }
  #pragma unroll
  for (int i = 0; i < 4; i++)
    #pragma unroll
    for (int j = 0; j < 2; j++)
      #pragma unroll
      for (int r = 0; r < 4; r++) {
        const int o = ow + i * 16 + fg * 4 + r;
        const int m = m0 + mw + j * 16 + fr;
        out[((size_t)b * DOUT + o) * MM + m] = acc[i][j][r];
      }
}

// ---------------- launch ----------------
#define XTB_OFF 0
#define PTS_OFF 33554432
#define AOUT_OFF 67108864
#define WB_OFF 201326592
#define ST_OFF 201850880

extern "C" void kernel_launch(void* const* d_in, const int* in_sizes, int n_in,
                              void* d_out, int out_size, void* d_ws, size_t ws_size,
                              hipStream_t stream) {
  const float* xyz  = (const float*)d_in[0];
  const float* x    = (const float*)d_in[1];
  const float* xyzc = (const float*)d_in[2];
  const int*   idx  = (const int*)d_in[3];
  const float* alpha = (const float*)d_in[4];
  const float* beta  = (const float*)d_in[5];
  const float* nrad  = (const float*)d_in[6];
  const float* w1 = (const float*)d_in[7];
  const float* g1 = (const float*)d_in[8];
  const float* b1 = (const float*)d_in[9];
  const float* w2 = (const float*)d_in[10];
  const float* g2 = (const float*)d_in[11];
  const float* b2 = (const float*)d_in[12];
  const float* w3 = (const float*)d_in[13];
  const float* cvw = (const float*)d_in[14];
  char* ws = (char*)d_ws;
  ushortT* xTb  = (ushortT*)(ws + XTB_OFF);
  float4*  pts4 = (float4*)(ws + PTS_OFF);
  ushortT* Aout = (ushortT*)(ws + AOUT_OFF);
  ushortT* Wb   = (ushortT*)(ws + WB_OFF);
  float*   st   = (float*)(ws + ST_OFF);
  float* out = (float*)d_out;

  hipMemsetAsync(st, 0, 4096, stream);
  kxT<<<dim3(NN / 32, DD / 32, BB), dim3(32, 8), 0, stream>>>(x, xTb);
  kWb<<<dim3(DOUT * TT / 256), 256, 0, stream>>>(cvw, Wb);
  kpassA<<<dim3(MM / 16, BB), 256, 0, stream>>>(xyz, xyzc, idx, w1, st, pts4);
  kS1<<<1, 64, 0, stream>>>(nrad, g1, b1, st);
  kpassB<<<dim3(MM / 16, BB), 256, 0, stream>>>(pts4, alpha, beta, w1, w2, st);
  kS2<<<1, 64, 0, stream>>>(g2, b2, st);
  kF1m<<<dim3(MM / 16, BB), 256, 0, stream>>>(pts4, idx, alpha, beta, w1, w2, w3, st, xTb, Aout);
  kgemm<<<dim3(MM / 128, BB), 512, 0, stream>>>(Wb, Aout, out);
}

// Round 12
// 210.645 us; speedup vs baseline: 1.1215x; 1.0119x over previous
//
#include <hip/hip_runtime.h>
#include <hip/hip_bf16.h>

#define BB 4
#define NN 32768
#define MM 8192
#define KK 16
#define DD 128
#define DOUT 128
#define TT 2048

typedef unsigned short ushortT;
typedef unsigned int uintT;
typedef __attribute__((ext_vector_type(8))) short short8;
typedef __attribute__((ext_vector_type(4))) float f32x4;
typedef __attribute__((ext_vector_type(2))) float f32x2;

__device__ __forceinline__ ushortT f2bf(float f) {
  union { float f; uintT u; } v; v.f = f;
  uintT u = v.u;
  return (ushortT)((u + 0x7FFFu + ((u >> 16) & 1u)) >> 16);
}

// stats layout (floats) in ws
#define ST_MAXD 0
#define ST_E1 16     // [b*32 + o] = sum, [b*32 + 16 + o] = sumsq
#define ST_A1 160
#define ST_B1 224
#define ST_E2 288
#define ST_A2 416
#define ST_B2 480

// ---------------- transpose x (B,D,N) f32 -> xTb (B,N,D) bf16 ----------------
__global__ __launch_bounds__(256) void kxT(const float* __restrict__ x, ushortT* __restrict__ xTb) {
  __shared__ float tile[32][33];
  const int b = blockIdx.z;
  const int n0 = blockIdx.x * 32, d0 = blockIdx.y * 32;
  const int tx = threadIdx.x, ty = threadIdx.y;
  const float* xp = x + (size_t)b * DD * NN;
  #pragma unroll
  for (int i = 0; i < 4; i++)
    tile[ty + i * 8][tx] = xp[(size_t)(d0 + ty + i * 8) * NN + n0 + tx];
  __syncthreads();
  ushortT* op = xTb + (size_t)b * NN * DD;
  #pragma unroll
  for (int i = 0; i < 4; i++)
    op[(size_t)(n0 + ty + i * 8) * DD + d0 + tx] = f2bf(tile[tx][ty + i * 8]);
}

// ---------------- cv_w f32 -> bf16 ----------------
__global__ __launch_bounds__(256) void kWb(const float* __restrict__ cw, ushortT* __restrict__ wb) {
  const int i = blockIdx.x * 256 + threadIdx.x;
  wb[i] = f2bf(cw[i]);
}

// ---------------- pass A: mean_radius + e1 stats + write pts4 ----------------
__global__ __launch_bounds__(256) void kpassA(const float* __restrict__ xyz,
    const float* __restrict__ xyzc, const int* __restrict__ idx,
    const float* __restrict__ w1, float* __restrict__ st, float4* __restrict__ pts4) {
  const int b = blockIdx.y;
  const int tid = threadIdx.x;
  const int mloc = tid >> 4, k = tid & 15;
  const int m = blockIdx.x * 16 + mloc;
  const int gi = (b * MM + m) * KK + k;
  const int n = idx[gi];
  const float cx = xyzc[(b * MM + m) * 3 + 0];
  const float cy = xyzc[(b * MM + m) * 3 + 1];
  const float cz = xyzc[(b * MM + m) * 3 + 2];
  const float* p = xyz + ((size_t)b * NN + n) * 3;
  const float px = p[0] - cx, py = p[1] - cy, pz = p[2] - cz;
  const float dist = sqrtf(px * px + py * py + pz * pz);
  pts4[gi] = (float4){px, py, pz, dist};
  float maxd = dist;
  maxd = fmaxf(maxd, __shfl_xor(maxd, 1));
  maxd = fmaxf(maxd, __shfl_xor(maxd, 2));
  maxd = fmaxf(maxd, __shfl_xor(maxd, 4));
  maxd = fmaxf(maxd, __shfl_xor(maxd, 8));
  __shared__ float red[16];
  __shared__ float wred[4][32];
  if (k == 0) red[mloc] = maxd;
  float vs[16], vq[16];
  #pragma unroll
  for (int o = 0; o < 16; o++) {
    float e = px * w1[3 * o] + py * w1[3 * o + 1] + pz * w1[3 * o + 2];
    vs[o] = e; vq[o] = e * e;
  }
  #pragma unroll
  for (int s = 1; s < 64; s <<= 1) {
    #pragma unroll
    for (int o = 0; o < 16; o++) {
      vs[o] += __shfl_xor(vs[o], s);
      vq[o] += __shfl_xor(vq[o], s);
    }
  }
  const int wv = tid >> 6, lane = tid & 63;
  if (lane == 0) {
    #pragma unroll
    for (int o = 0; o < 16; o++) { wred[wv][o] = vs[o]; wred[wv][16 + o] = vq[o]; }
  }
  __syncthreads();
  if (tid < 32) {
    float a = wred[0][tid] + wred[1][tid] + wred[2][tid] + wred[3][tid];
    atomicAdd(&st[ST_E1 + b * 32 + tid], a);
  }
  if (tid == 0) {
    float s = 0.f;
    #pragma unroll
    for (int i = 0; i < 16; i++) s += red[i];
    atomicAdd(&st[ST_MAXD], s);
  }
}

// ---------------- finalize 1: nr, A1/B1 ----------------
__global__ void kS1(const float* __restrict__ nrad, const float* __restrict__ g1,
                    const float* __restrict__ b1, float* __restrict__ st) {
  const int tid = threadIdx.x;
  if (tid >= 64) return;
  const float meanrad = st[ST_MAXD] / (float)(BB * MM);
  const float nr = nrad[0] * 0.9f + meanrad * 0.1f;
  const int b = tid >> 4, o = tid & 15;
  const float cnt = (float)(MM * KK);
  const float sum = st[ST_E1 + b * 32 + o];
  const float sq  = st[ST_E1 + b * 32 + 16 + o];
  const float mu = sum / cnt;
  float var = sq / cnt - mu * mu; var = fmaxf(var, 0.f);
  const float invs = rsqrtf(var + 1e-5f * nr * nr);
  const float a = invs * g1[o];
  st[ST_A1 + b * 16 + o] = a;
  st[ST_B1 + b * 16 + o] = b1[o] - mu * a;
}

// ---------------- pass B: e2 stats (pure stream from pts4) ----------------
__global__ __launch_bounds__(256) void kpassB(const float4* __restrict__ pts4,
    const float* __restrict__ alpha, const float* __restrict__ beta,
    const float* __restrict__ w1, const float* __restrict__ w2,
    float* __restrict__ st) {
  const int b = blockIdx.y;
  const int tid = threadIdx.x;
  __shared__ float w2s[512];
  __shared__ float wred[4][32];
  w2s[tid] = w2[tid]; w2s[256 + tid] = w2[256 + tid];
  const int gi = b * MM * KK + blockIdx.x * 256 + tid;
  const float4 p4 = pts4[gi];
  const float px = p4.x, py = p4.y, pz = p4.z, dist = p4.w;
  float dwv = 1.f / (1.f + expf(alpha[0] * dist - beta[0]));
  float s = dwv;
  s += __shfl_xor(s, 1); s += __shfl_xor(s, 2); s += __shfl_xor(s, 4); s += __shfl_xor(s, 8);
  s = s + (s == 0.f ? 1.f : 0.f) + 1e-6f;
  dwv = dwv / s * 16.f;
  float mat1[16], mp1[16];
  #pragma unroll
  for (int o = 0; o < 16; o++) {
    float e = px * w1[3 * o] + py * w1[3 * o + 1] + pz * w1[3 * o + 2];
    float v = e * st[ST_A1 + b * 16 + o] + st[ST_B1 + b * 16 + o];
    mat1[o] = fmaxf(v, 0.f);
    float t = mat1[o] * dwv;
    t = fmaxf(t, __shfl_xor(t, 1)); t = fmaxf(t, __shfl_xor(t, 2));
    t = fmaxf(t, __shfl_xor(t, 4)); t = fmaxf(t, __shfl_xor(t, 8));
    mp1[o] = t;
  }
  __syncthreads();  // w2s ready
  float vs[16], vq[16];
  #pragma unroll
  for (int o = 0; o < 16; o++) {
    float acc = 0.f;
    #pragma unroll
    for (int c = 0; c < 16; c++)
      acc += mat1[c] * w2s[o * 32 + c] + mp1[c] * w2s[o * 32 + 16 + c];
    vs[o] = acc; vq[o] = acc * acc;
  }
  #pragma unroll
  for (int s2 = 1; s2 < 64; s2 <<= 1) {
    #pragma unroll
    for (int o = 0; o < 16; o++) {
      vs[o] += __shfl_xor(vs[o], s2);
      vq[o] += __shfl_xor(vq[o], s2);
    }
  }
  const int wv = tid >> 6, lane = tid & 63;
  if (lane == 0) {
    #pragma unroll
    for (int o = 0; o < 16; o++) { wred[wv][o] = vs[o]; wred[wv][16 + o] = vq[o]; }
  }
  __syncthreads();
  if (tid < 32) {
    float a = wred[0][tid] + wred[1][tid] + wred[2][tid] + wred[3][tid];
    atomicAdd(&st[ST_E2 + b * 32 + tid], a);
  }
}

// ---------------- finalize 2: A2/B2 ----------------
__global__ void kS2(const float* __restrict__ g2, const float* __restrict__ b2,
                    float* __restrict__ st) {
  const int tid = threadIdx.x;
  if (tid >= 64) return;
  const int b = tid >> 4, o = tid & 15;
  const float cnt = (float)(MM * KK);
  const float sum = st[ST_E2 + b * 32 + o];
  const float sq  = st[ST_E2 + b * 32 + 16 + o];
  const float mu = sum / cnt;
  float var = sq / cnt - mu * mu; var = fmaxf(var, 0.f);
  const float invs = rsqrtf(var + 1e-5f);
  const float a = invs * g2[o];
  st[ST_A2 + b * 16 + o] = a;
  st[ST_B2 + b * 16 + o] = b2[o] - mu * a;
}

// ---------------- F1 ----------------
// FINAL (R12 = R6 revert): best verified configuration, 212.5us total.
// Session findings baked into this kernel:
//  - weights via s_load from global (R6: LDS-broadcast DS-pipe diet; w-barrier
//    removed; LDS = mat3s only, 32KB)
//  - 2-buffer 16-deep gather pipeline (R4: +28us total), PREF(xA) before
//    layers 2/3 fits the (512,4)=128-reg budget HERE because acc is only
//    32 f32 (jh-split) -- the m-pair variant (64-f32 acc) provably cannot
//    fit phase1+buffers in any pin tried (R9/R10/R11 all spilled).
//  - f32x2 v_pk_fma packing throughout (R5)
//  - quad-XOR swizzled mat3s (R2)
// Known structure-bound: kF1 ~117us at all pipes <=46% -- latency-bound
// monolith; split (R7/R8) and m-pair fusion (R9-R11) both measured worse.
__global__ __launch_bounds__(512, 4) void kF1(const float4* __restrict__ pts4,
    const int* __restrict__ idx,
    const float* __restrict__ alpha, const float* __restrict__ beta,
    const float* __restrict__ w1, const float* __restrict__ w2, const float* __restrict__ w3,
    const float* __restrict__ st, const ushortT* __restrict__ xTb, ushortT* __restrict__ Aout) {
  __shared__ float mat3s[32 * 256];      // [m][k*16 + (q^swz(k))*4 + j0]
  const int b = blockIdx.y;
  const int tid = threadIdx.x;
  const int m0 = blockIdx.x * 32;

  const int mloc = tid >> 4, k1 = tid & 15;
  const int gi = (b * MM + m0) * KK + tid;
  const float4 p4 = pts4[gi];
  const float px = p4.x, py = p4.y, pz = p4.z, dist = p4.w;
  float dwv = 1.f / (1.f + expf(alpha[0] * dist - beta[0]));
  {
    float s = dwv;
    s += __shfl_xor(s, 1); s += __shfl_xor(s, 2); s += __shfl_xor(s, 4); s += __shfl_xor(s, 8);
    s = s + (s == 0.f ? 1.f : 0.f) + 1e-6f;
    dwv = dwv / s * 16.f;
  }

  // layer 1 -> v1 pairs: logical in1[i], i<16: mat1[o]; i>=16: mp1[o]
  f32x2 v1[16];
  #pragma unroll
  for (int o = 0; o < 16; o++) {
    float e = px * w1[3 * o] + py * w1[3 * o + 1] + pz * w1[3 * o + 2];
    float v = e * st[ST_A1 + b * 16 + o] + st[ST_B1 + b * 16 + o];
    v = fmaxf(v, 0.f);
    float t = v * dwv;
    t = fmaxf(t, __shfl_xor(t, 1)); t = fmaxf(t, __shfl_xor(t, 2));
    t = fmaxf(t, __shfl_xor(t, 4)); t = fmaxf(t, __shfl_xor(t, 8));
    if (o & 1) { v1[o >> 1].y = v; v1[8 + (o >> 1)].y = t; }
    else       { v1[o >> 1].x = v; v1[8 + (o >> 1)].x = t; }
  }

  // ---- phase-2 geometry + early prefetch of gather group 0 ----
  const int wid = __builtin_amdgcn_readfirstlane(tid >> 6);
  const int lane = tid & 63;
  const int jh = lane >> 5;
  const int dq = lane & 31;
  const int d0 = dq * 4;
  const int jq0 = jh * 2;
  const ushortT* xb = xTb + (size_t)b * NN * DD + d0;

  uint2 xA[16], xB[16];

#define PREF(dst, gg) do {                                                 \
    const int* ib = idx + (((b * MM + m0 + (gg) * 8 + wid)) << 4);         \
    _Pragma("unroll")                                                      \
    for (int k = 0; k < 16; k++) {                                         \
      const uintT nn = (uintT)ib[k];                                       \
      (dst)[k] = *(const uint2*)(xb + ((size_t)nn << 7));                  \
    }                                                                      \
  } while (0)

  PREF(xA, 0);  // in flight under layers 2/3

  // layer 2: weights from global (uniform -> s_load), pk_fma along c-pairs
  {
    float in2[16];
    #pragma unroll
    for (int o = 0; o < 16; o++) {
      f32x2 acc = {0.f, 0.f};
      #pragma unroll
      for (int cp = 0; cp < 16; cp++) {
        const f32x2 wv = *(const f32x2*)(w2 + o * 32 + 2 * cp);
        acc += v1[cp] * wv;
      }
      float v = (acc.x + acc.y) * st[ST_A2 + b * 16 + o] + st[ST_B2 + b * 16 + o];
      in2[o] = fmaxf(v, 0.f);
    }
    f32x2 v2[16];
    #pragma unroll
    for (int o = 0; o < 16; o++) {
      float t = in2[o] * dwv;
      t = fmaxf(t, __shfl_xor(t, 1)); t = fmaxf(t, __shfl_xor(t, 2));
      t = fmaxf(t, __shfl_xor(t, 4)); t = fmaxf(t, __shfl_xor(t, 8));
      if (o & 1) { v2[o >> 1].y = in2[o]; v2[8 + (o >> 1)].y = t; }
      else       { v2[o >> 1].x = in2[o]; v2[8 + (o >> 1)].x = t; }
    }
    // layer 3
    float m3v[16];
    #pragma unroll
    for (int j = 0; j < 16; j++) {
      f32x2 acc = {0.f, 0.f};
      #pragma unroll
      for (int cp = 0; cp < 16; cp++) {
        const f32x2 wv = *(const f32x2*)(w3 + j * 32 + 2 * cp);
        acc += v2[cp] * wv;
      }
      m3v[j] = fmaxf(acc.x + acc.y, 0.f) * dwv;
    }
    const int swz1 = (k1 ^ (k1 >> 2)) & 3;
    float* m3w = &mat3s[mloc * 256 + k1 * 16];
    #pragma unroll
    for (int q = 0; q < 4; q++)
      *(f32x4*)(m3w + ((q ^ swz1) << 2)) =
          (f32x4){m3v[4 * q], m3v[4 * q + 1], m3v[4 * q + 2], m3v[4 * q + 3]};
  }
  __syncthreads();  // mat3s ready (xA loads already complete)

#define COMP(src, gg) do {                                                 \
    const int ml = (gg) * 8 + wid;                                         \
    const float* m3base = &mat3s[ml * 256];                                \
    f32x2 a2[4][4];                                                        \
    _Pragma("unroll")                                                      \
    for (int d = 0; d < 4; d++)                                            \
      _Pragma("unroll")                                                    \
      for (int c = 0; c < 4; c++) a2[d][c] = (f32x2){0.f, 0.f};            \
    _Pragma("unroll")                                                      \
    for (int k = 0; k < 16; k++) {                                         \
      const int sw = (k ^ (k >> 2)) & 3;                                   \
      const uint2 xv = (src)[k];                                           \
      const f32x4 mq0 = *(const f32x4*)(m3base + k * 16 + ((jq0 ^ sw) << 2));        \
      const f32x4 mq1 = *(const f32x4*)(m3base + k * 16 + (((jq0 + 1) ^ sw) << 2));  \
      float xs[4];                                                         \
      xs[0] = __uint_as_float(xv.x << 16);                                 \
      xs[1] = __uint_as_float(xv.x & 0xFFFF0000u);                         \
      xs[2] = __uint_as_float(xv.y << 16);                                 \
      xs[3] = __uint_as_float(xv.y & 0xFFFF0000u);                         \
      f32x2 mp[4];                                                         \
      mp[0] = mq0.lo; mp[1] = mq0.hi;                                      \
      mp[2] = mq1.lo; mp[3] = mq1.hi;                                      \
      _Pragma("unroll")                                                    \
      for (int d = 0; d < 4; d++) {                                        \
        const float xd = xs[d];                                            \
        _Pragma("unroll")                                                  \
        for (int c = 0; c < 4; c++)                                        \
          a2[d][c] += mp[c] * xd;                                          \
      }                                                                    \
    }                                                                      \
    ushortT* aop = Aout + ((size_t)b * MM + m0 + ml) * TT + d0 * 16 + jh * 8;  \
    _Pragma("unroll")                                                      \
    for (int d = 0; d < 4; d++) {                                          \
      uintT u[4];                                                          \
      _Pragma("unroll")                                                    \
      for (int c = 0; c < 4; c++)                                          \
        u[c] = (uintT)f2bf(a2[d][c].x) | ((uintT)f2bf(a2[d][c].y) << 16);  \
      *(uint4*)(aop + d * 16) = (uint4){u[0], u[1], u[2], u[3]};           \
    }                                                                      \
  } while (0)

  PREF(xB, 1);
  COMP(xA, 0);
  PREF(xA, 2);
  COMP(xB, 1);
  PREF(xB, 3);
  COMP(xA, 2);
  COMP(xB, 3);

#undef PREF
#undef COMP
}

// ---------------- GEMM: out[b,o,m] = sum_t Wb[o,t] * Aout[b,m,t] ----------------
__global__ __launch_bounds__(512) void kgemm(const ushortT* __restrict__ Wb,
                                             const ushortT* __restrict__ Aout,
                                             float* __restrict__ out) {
  __shared__ ushortT At[128 * 40];
  __shared__ ushortT Bt[128 * 40];
  const int b = blockIdx.y;
  const int m0 = blockIdx.x * 128;
  const int tid = threadIdx.x;
  const int w = tid >> 6, l = tid & 63;
  const int ow = (w >> 2) * 64, mw = (w & 3) * 32;
  const int fr = l & 15, fg = l >> 4;
  f32x4 acc[4][2];
  #pragma unroll
  for (int i = 0; i < 4; i++)
    #pragma unroll
    for (int j = 0; j < 2; j++)
      acc[i][j] = (f32x4){0.f, 0.f, 0.f, 0.f};
  const int srow = tid >> 2, sk = (tid & 3) * 8;
  const ushortT* wp = Wb + srow * TT + sk;
  const ushortT* ap = Aout + ((size_t)b * MM + m0 + srow) * TT + sk;
  for (int k0 = 0; k0 < TT; k0 += 32) {
    uint4 wv = *(const uint4*)(wp + k0);
    uint4 av = *(const uint4*)(ap + k0);
    *(uint4*)&At[srow * 40 + sk] = wv;
    *(uint4*)&Bt[srow * 40 + sk] = av;
    __syncthreads();
    short8 a[4], bfrag[2];
    #pragma unroll
    for (int i = 0; i < 4; i++) a[i] = *(short8*)&At[(ow + i * 16 + fr) * 40 + fg * 8];
    #pragma unroll
    for (int j = 0; j < 2; j++) bfrag[j] = *(short8*)&Bt[(mw + j * 16 + fr) * 40 + fg * 8];
    #pragma unroll
    for (int i = 0; i < 4; i++)
      #pragma unroll
      for (int j = 0; j < 2; j++)
        acc[i][j] = __builtin_amdgcn_mfma_f32_16x16x32_bf16(a[i], bfrag[j], acc[i][j], 0, 0, 0);
    __syncthreads();
  }
  #pragma unroll
  for (int i = 0; i < 4; i++)
    #pragma unroll
    for (int j = 0; j < 2; j++)
      #pragma unroll
      for (int r = 0; r < 4; r++) {
        const int o = ow + i * 16 + fg * 4 + r;
        const int m = m0 + mw + j * 16 + fr;
        out[((size_t)b * DOUT + o) * MM + m] = acc[i][j][r];
      }
}

// ---------------- launch ----------------
#define XTB_OFF 0
#define PTS_OFF 33554432
#define AOUT_OFF 67108864
#define WB_OFF 201326592
#define ST_OFF 201850880

extern "C" void kernel_launch(void* const* d_in, const int* in_sizes, int n_in,
                              void* d_out, int out_size, void* d_ws, size_t ws_size,
                              hipStream_t stream) {
  const float* xyz  = (const float*)d_in[0];
  const float* x    = (const float*)d_in[1];
  const float* xyzc = (const float*)d_in[2];
  const int*   idx  = (const int*)d_in[3];
  const float* alpha = (const float*)d_in[4];
  const float* beta  = (const float*)d_in[5];
  const float* nrad  = (const float*)d_in[6];
  const float* w1 = (const float*)d_in[7];
  const float* g1 = (const float*)d_in[8];
  const float* b1 = (const float*)d_in[9];
  const float* w2 = (const float*)d_in[10];
  const float* g2 = (const float*)d_in[11];
  const float* b2 = (const float*)d_in[12];
  const float* w3 = (const float*)d_in[13];
  const float* cvw = (const float*)d_in[14];
  char* ws = (char*)d_ws;
  ushortT* xTb  = (ushortT*)(ws + XTB_OFF);
  float4*  pts4 = (float4*)(ws + PTS_OFF);
  ushortT* Aout = (ushortT*)(ws + AOUT_OFF);
  ushortT* Wb   = (ushortT*)(ws + WB_OFF);
  float*   st   = (float*)(ws + ST_OFF);
  float* out = (float*)d_out;

  hipMemsetAsync(st, 0, 4096, stream);
  kxT<<<dim3(NN / 32, DD / 32, BB), dim3(32, 8), 0, stream>>>(x, xTb);
  kWb<<<dim3(DOUT * TT / 256), 256, 0, stream>>>(cvw, Wb);
  kpassA<<<dim3(MM / 16, BB), 256, 0, stream>>>(xyz, xyzc, idx, w1, st, pts4);
  kS1<<<1, 64, 0, stream>>>(nrad, g1, b1, st);
  kpassB<<<dim3(MM / 16, BB), 256, 0, stream>>>(pts4, alpha, beta, w1, w2, st);
  kS2<<<1, 64, 0, stream>>>(g2, b2, st);
  kF1<<<dim3(MM / 32, BB), 512, 0, stream>>>(pts4, idx, alpha, beta, w1, w2, w3, st, xTb, Aout);
  kgemm<<<dim3(MM / 128, BB), 512, 0, stream>>>(Wb, Aout, out);
}